// Round 1
// baseline (426.018 us; speedup 1.0000x reference)
//
#include <hip/hip_runtime.h>
#include <hip/hip_bf16.h>

// Problem constants
#define D_MODEL 768
#define SEQL    2048
#define BATCH   8
#define NSTATE  16
#define NCHUNK  32
#define TCHUNK  64   // SEQL / NCHUNK

typedef __attribute__((ext_vector_type(8))) short short8;
typedef __attribute__((ext_vector_type(4))) float f32x4;

typedef const __attribute__((address_space(1))) unsigned int gas1_t;
typedef __attribute__((address_space(3))) unsigned int las3_t;

__device__ __forceinline__ void gload_lds16(const void* g, void* l) {
  __builtin_amdgcn_global_load_lds((gas1_t*)g, (las3_t*)l, 16, 0, 0);
}

// ---------------------------------------------------------------------------
// Conversion kernels
// ---------------------------------------------------------------------------
__global__ __launch_bounds__(256) void f32_to_bf16_x4(const float* __restrict__ in,
                                                      __hip_bfloat16* __restrict__ out) {
  int i = (blockIdx.x * 256 + threadIdx.x) * 4;
  float4 v = *(const float4*)(in + i);
  out[i + 0] = __float2bfloat16(v.x);
  out[i + 1] = __float2bfloat16(v.y);
  out[i + 2] = __float2bfloat16(v.z);
  out[i + 3] = __float2bfloat16(v.w);
}

__global__ __launch_bounds__(256) void prep_weights(
    const float* __restrict__ in_w, const float* __restrict__ delta_w,
    const float* __restrict__ Bp, const float* __restrict__ Cp,
    const float* __restrict__ out_w, const float* __restrict__ A_log,
    __hip_bfloat16* __restrict__ w_in, __hip_bfloat16* __restrict__ w_dbc,
    __hip_bfloat16* __restrict__ w_out, float* __restrict__ A2) {
  int i = blockIdx.x * 256 + threadIdx.x;
  if (i < 1536 * 768) { w_in[i] = __float2bfloat16(in_w[i]); return; }
  i -= 1536 * 768;
  if (i < 896 * 768) {
    int row = i / 768, col = i - row * 768;
    float v;
    if (row < 768)      v = delta_w[row * 768 + col];
    else if (row < 784) v = Bp[(row - 768) * 768 + col];
    else if (row < 800) v = Cp[(row - 784) * 768 + col];
    else                v = 0.f;
    w_dbc[i] = __float2bfloat16(v);
    return;
  }
  i -= 896 * 768;
  if (i < 768 * 768) { w_out[i] = __float2bfloat16(out_w[i]); return; }
  i -= 768 * 768;
  if (i < 768 * 16) A2[i] = -expf(A_log[i]) * 1.44269504088896f;  // A * log2(e)
}

// ---------------------------------------------------------------------------
// bf16 MFMA GEMM, C[M,N] = A[M,K] * B[N,K]^T  (both row-major, K fast)
// 128x128 tile, BK=32, 4 waves (2x2), each wave 64x64 (4x4 16x16 frags).
// MODE 0: in_proj   -> bf16 x_in (col<768), bf16 z (col>=768), +bias
// MODE 1: dbc       -> fp32 softplus(delta)+bias (col<768), fp32 B (768..783),
//                      fp32 C (784..799), skip >=800
// MODE 2: out_proj  -> fp32 out + bias
// ---------------------------------------------------------------------------
template <int MODE>
__global__ __launch_bounds__(256) void gemm_bt(
    const __hip_bfloat16* __restrict__ A, const __hip_bfloat16* __restrict__ Bw,
    const float* __restrict__ bias, void* __restrict__ out0,
    void* __restrict__ out1, void* __restrict__ out2, int K) {
  __shared__ __hip_bfloat16 sA[128 * 32];
  __shared__ __hip_bfloat16 sB[128 * 32];
  const int tid  = threadIdx.x;
  const int lane = tid & 63, wave = tid >> 6;
  const int wr = wave >> 1, wc = wave & 1;
  const int rowA0 = blockIdx.y * 128;
  const int rowB0 = blockIdx.x * 128;

  f32x4 acc[4][4] = {};

  for (int kt = 0; kt < K; kt += 32) {
    __syncthreads();
#pragma unroll
    for (int s = 0; s < 2; ++s) {
      const unsigned off = s * 4096 + tid * 16;  // byte offset within 8KB tile
      const unsigned r = off >> 6, cb = off & 63;
      gload_lds16((const char*)(A + (size_t)(rowA0 + r) * K + kt) + cb,
                  (char*)sA + off);
      gload_lds16((const char*)(Bw + (size_t)(rowB0 + r) * K + kt) + cb,
                  (char*)sB + off);
    }
    __syncthreads();  // compiler emits vmcnt(0) drain before barrier

    short8 a[4], b[4];
#pragma unroll
    for (int m = 0; m < 4; ++m)
      a[m] = *(const short8*)((const char*)sA + (wr * 64 + m * 16 + (lane & 15)) * 64 +
                              ((lane >> 4) << 4));
#pragma unroll
    for (int n = 0; n < 4; ++n)
      b[n] = *(const short8*)((const char*)sB + (wc * 64 + n * 16 + (lane & 15)) * 64 +
                              ((lane >> 4) << 4));
#pragma unroll
    for (int m = 0; m < 4; ++m)
#pragma unroll
      for (int n = 0; n < 4; ++n)
        acc[m][n] = __builtin_amdgcn_mfma_f32_16x16x32_bf16(a[m], b[n], acc[m][n], 0, 0, 0);
  }

  // epilogue (C/D layout: col = lane&15, row = (lane>>4)*4 + i)
#pragma unroll
  for (int m = 0; m < 4; ++m) {
    const int grow_base = rowA0 + wr * 64 + m * 16 + ((lane >> 4) << 2);
#pragma unroll
    for (int n = 0; n < 4; ++n) {
      const int gcol = rowB0 + wc * 64 + n * 16 + (lane & 15);
#pragma unroll
      for (int i = 0; i < 4; ++i) {
        const size_t grow = grow_base + i;
        float v = acc[m][n][i];
        if (MODE == 0) {
          v += bias[gcol];
          if (gcol < 768)
            ((__hip_bfloat16*)out0)[grow * 768 + gcol] = __float2bfloat16(v);
          else
            ((__hip_bfloat16*)out1)[grow * 768 + gcol - 768] = __float2bfloat16(v);
        } else if (MODE == 1) {
          if (gcol < 768) {
            v += bias[gcol];
            float sp = (v > 20.f) ? v : log1pf(expf(v));
            ((float*)out0)[grow * 768 + gcol] = sp;
          } else if (gcol < 784) {
            ((float*)out1)[grow * 16 + (gcol - 768)] = v;
          } else if (gcol < 800) {
            ((float*)out2)[grow * 16 + (gcol - 784)] = v;
          }
        } else {
          ((float*)out0)[grow * 768 + gcol] = v + bias[gcol];
        }
      }
    }
  }
}

// ---------------------------------------------------------------------------
// Depthwise conv1d (K=3, pad=1) + bias + SiLU.  x_in bf16 -> x_conv bf16
// ---------------------------------------------------------------------------
__global__ __launch_bounds__(256) void conv_silu(
    const __hip_bfloat16* __restrict__ xin, const float* __restrict__ conv_w,
    const float* __restrict__ conv_b, __hip_bfloat16* __restrict__ xc) {
  const int idx = blockIdx.x * 256 + threadIdx.x;  // over B*L*D
  const int d = idx % 768;
  const int t = (idx / 768) % SEQL;
  const float w0 = conv_w[d * 3], w1 = conv_w[d * 3 + 1], w2 = conv_w[d * 3 + 2];
  float acc = conv_b[d];
  float xm = (t > 0)        ? __bfloat162float(xin[idx - 768]) : 0.f;
  float x0 = __bfloat162float(xin[idx]);
  float xp = (t < SEQL - 1) ? __bfloat162float(xin[idx + 768]) : 0.f;
  acc += w0 * xm + w1 * x0 + w2 * xp;
  const float sig = 1.f / (1.f + __expf(-acc));
  xc[idx] = __float2bfloat16(acc * sig);
}

// ---------------------------------------------------------------------------
// Scan pass 1: per (b, d, chunk) local scan with h_in = 0; emits final local
// state S[b][c][n][d] and sum_dt[b][c][d].
// ---------------------------------------------------------------------------
__global__ __launch_bounds__(256) void scan_pass1(
    const float* __restrict__ delta, const __hip_bfloat16* __restrict__ xconv,
    const float* __restrict__ Bsel, const float* __restrict__ A2,
    float* __restrict__ sumdt, float* __restrict__ Sbuf) {
  const int d = blockIdx.x * 256 + threadIdx.x;
  const int b = blockIdx.y, c = blockIdx.z;
  __shared__ float sB[TCHUNK * 16];
  ((float4*)sB)[threadIdx.x] =
      ((const float4*)(Bsel + ((size_t)b * SEQL + c * TCHUNK) * 16))[threadIdx.x];
  __syncthreads();

  float a2[16];
#pragma unroll
  for (int n = 0; n < 16; ++n) a2[n] = A2[d * 16 + n];
  float h[16] = {};
  float sdt = 0.f;
  const size_t base = ((size_t)b * SEQL + c * TCHUNK) * 768 + d;
  for (int t = 0; t < TCHUNK; ++t) {
    const float dt = delta[base + (size_t)t * 768];
    const float x = __bfloat162float(xconv[base + (size_t)t * 768]);
    sdt += dt;
    const float dtx = dt * x;
    const float* Br = &sB[t * 16];
#pragma unroll
    for (int n = 0; n < 16; ++n) {
      const float a = exp2f(dt * a2[n]);
      h[n] = fmaf(a, h[n], dtx * Br[n]);
    }
  }
  sumdt[((size_t)b * NCHUNK + c) * 768 + d] = sdt;
#pragma unroll
  for (int n = 0; n < 16; ++n)
    Sbuf[(((size_t)b * NCHUNK + c) * 16 + n) * 768 + d] = h[n];
}

// ---------------------------------------------------------------------------
// Scan pass 2: serial carry over chunks. h_in[c] = P_{c-1} h_in[c-1] + S_{c-1},
// P_c = exp2(A2 * sum_dt_c).  6144 threads.
// ---------------------------------------------------------------------------
__global__ __launch_bounds__(256) void scan_carry(
    const float* __restrict__ sumdt, const float* __restrict__ Sbuf,
    const float* __restrict__ A2, float* __restrict__ Hin) {
  const int idx = blockIdx.x * 256 + threadIdx.x;  // 0..6143
  const int b = idx / 768, d = idx - b * 768;
  float a2[16];
#pragma unroll
  for (int n = 0; n < 16; ++n) a2[n] = A2[d * 16 + n];
  float h[16] = {};
  for (int c = 0; c < NCHUNK; ++c) {
    const size_t hb = ((size_t)b * NCHUNK + c) * 16 * 768 + d;
#pragma unroll
    for (int n = 0; n < 16; ++n) Hin[hb + (size_t)n * 768] = h[n];
    const float sd = sumdt[((size_t)b * NCHUNK + c) * 768 + d];
#pragma unroll
    for (int n = 0; n < 16; ++n) {
      const float P = exp2f(sd * a2[n]);
      h[n] = fmaf(P, h[n], Sbuf[hb + (size_t)n * 768]);
    }
  }
}

// ---------------------------------------------------------------------------
// Scan pass 3: replay with correct h_in, compute y, fuse D-skip + silu(z)
// gating, emit bf16 y_gated.
// ---------------------------------------------------------------------------
__global__ __launch_bounds__(256) void scan_pass3(
    const float* __restrict__ delta, const __hip_bfloat16* __restrict__ xconv,
    const __hip_bfloat16* __restrict__ zb, const float* __restrict__ Bsel,
    const float* __restrict__ Csel, const float* __restrict__ A2,
    const float* __restrict__ Hin, const float* __restrict__ Dp,
    __hip_bfloat16* __restrict__ yg) {
  const int d = blockIdx.x * 256 + threadIdx.x;
  const int b = blockIdx.y, c = blockIdx.z;
  __shared__ float sB[TCHUNK * 16], sC[TCHUNK * 16];
  {
    const size_t off = ((size_t)b * SEQL + c * TCHUNK) * 16;
    ((float4*)sB)[threadIdx.x] = ((const float4*)(Bsel + off))[threadIdx.x];
    ((float4*)sC)[threadIdx.x] = ((const float4*)(Csel + off))[threadIdx.x];
  }
  __syncthreads();

  float a2[16];
#pragma unroll
  for (int n = 0; n < 16; ++n) a2[n] = A2[d * 16 + n];
  float h[16];
  {
    const size_t hb = ((size_t)b * NCHUNK + c) * 16 * 768 + d;
#pragma unroll
    for (int n = 0; n < 16; ++n) h[n] = Hin[hb + (size_t)n * 768];
  }
  const float Dpd = Dp[d];
  const size_t base = ((size_t)b * SEQL + c * TCHUNK) * 768 + d;
  for (int t = 0; t < TCHUNK; ++t) {
    const float dt = delta[base + (size_t)t * 768];
    const float x = __bfloat162float(xconv[base + (size_t)t * 768]);
    const float dtx = dt * x;
    const float* Br = &sB[t * 16];
    const float* Cr = &sC[t * 16];
    float y = 0.f;
#pragma unroll
    for (int n = 0; n < 16; ++n) {
      const float a = exp2f(dt * a2[n]);
      h[n] = fmaf(a, h[n], dtx * Br[n]);
      y = fmaf(h[n], Cr[n], y);
    }
    const float z = __bfloat162float(zb[base + (size_t)t * 768]);
    const float sig = 1.f / (1.f + __expf(-z));
    const float out = (y + x * Dpd) * (z * sig);
    yg[base + (size_t)t * 768] = __float2bfloat16(out);
  }
}

// ---------------------------------------------------------------------------
// Launch
// ---------------------------------------------------------------------------
extern "C" void kernel_launch(void* const* d_in, const int* in_sizes, int n_in,
                              void* d_out, int out_size, void* d_ws, size_t ws_size,
                              hipStream_t stream) {
  const float* x       = (const float*)d_in[0];
  const float* A_log   = (const float*)d_in[1];
  const float* D_param = (const float*)d_in[2];
  const float* B_proj  = (const float*)d_in[3];
  const float* C_proj  = (const float*)d_in[4];
  const float* delta_w = (const float*)d_in[5];
  const float* delta_b = (const float*)d_in[6];
  const float* in_w    = (const float*)d_in[7];
  const float* in_b    = (const float*)d_in[8];
  const float* out_w   = (const float*)d_in[9];
  const float* out_b   = (const float*)d_in[10];
  const float* conv_w  = (const float*)d_in[11];
  const float* conv_b  = (const float*)d_in[12];

  char* ws = (char*)d_ws;
  __hip_bfloat16* xb      = (__hip_bfloat16*)(ws + 0);
  __hip_bfloat16* w_in_b  = (__hip_bfloat16*)(ws + 25165824);
  __hip_bfloat16* w_dbc_b = (__hip_bfloat16*)(ws + 27525120);
  __hip_bfloat16* w_out_b = (__hip_bfloat16*)(ws + 28901376);
  float*          A2      = (float*)(ws + 30081024);
  __hip_bfloat16* xin_b   = (__hip_bfloat16*)(ws + 30130176);
  __hip_bfloat16* z_b     = (__hip_bfloat16*)(ws + 55296000);
  __hip_bfloat16* xconv_b = (__hip_bfloat16*)(ws + 80461824);
  float*          delta_f = (float*)(ws + 105627648);
  float*          Bsel    = (float*)(ws + 155959296);
  float*          Csel    = (float*)(ws + 157007872);
  float*          sumdt   = (float*)(ws + 158056448);
  float*          Sbuf    = (float*)(ws + 158842880);
  float*          Hin     = (float*)(ws + 171425792);
  __hip_bfloat16* yg      = (__hip_bfloat16*)(ws + 184008704);

  const int BLD = BATCH * SEQL * D_MODEL;  // 12,582,912

  // 1. x -> bf16
  f32_to_bf16_x4<<<BLD / 4 / 256, 256, 0, stream>>>(x, xb);
  // 2. weights -> bf16 (+ A2 table)
  prep_weights<<<(1536 * 768 + 896 * 768 + 768 * 768 + 768 * 16) / 256, 256, 0, stream>>>(
      in_w, delta_w, B_proj, C_proj, out_w, A_log, w_in_b, w_dbc_b, w_out_b, A2);
  // 3. in_proj GEMM [16384,1536]
  gemm_bt<0><<<dim3(12, 128), 256, 0, stream>>>(xb, w_in_b, in_b, xin_b, z_b, nullptr, 768);
  // 4. depthwise conv + silu
  conv_silu<<<BLD / 256, 256, 0, stream>>>(xin_b, conv_w, conv_b, xconv_b);
  // 5. delta/B/C GEMM [16384,896]
  gemm_bt<1><<<dim3(7, 128), 256, 0, stream>>>(xconv_b, w_dbc_b, delta_b, delta_f, Bsel, Csel, 768);
  // 6-8. chunked scan
  scan_pass1<<<dim3(3, BATCH, NCHUNK), 256, 0, stream>>>(delta_f, xconv_b, Bsel, A2, sumdt, Sbuf);
  scan_carry<<<24, 256, 0, stream>>>(sumdt, Sbuf, A2, Hin);
  scan_pass3<<<dim3(3, BATCH, NCHUNK), 256, 0, stream>>>(delta_f, xconv_b, z_b, Bsel, Csel, A2,
                                                         Hin, D_param, yg);
  // 9. out_proj GEMM [16384,768] -> d_out
  gemm_bt<2><<<dim3(6, 128), 256, 0, stream>>>(yg, w_out_b, out_b, (float*)d_out, nullptr,
                                               nullptr, 768);
}

// Round 2
// 398.972 us; speedup vs baseline: 1.0678x; 1.0678x over previous
//
#include <hip/hip_runtime.h>
#include <hip/hip_bf16.h>

// Problem constants
#define D_MODEL 768
#define SEQL    2048
#define BATCH   8
#define NSTATE  16
#define NCHUNK  32
#define TCHUNK  64   // SEQL / NCHUNK

typedef __attribute__((ext_vector_type(8))) short short8;
typedef __attribute__((ext_vector_type(4))) float f32x4;

typedef const __attribute__((address_space(1))) unsigned int gas1_t;
typedef __attribute__((address_space(3))) unsigned int las3_t;

__device__ __forceinline__ void gload_lds16(const void* g, void* l) {
  __builtin_amdgcn_global_load_lds((gas1_t*)g, (las3_t*)l, 16, 0, 0);
}

// ---------------------------------------------------------------------------
// Conversion kernels
// ---------------------------------------------------------------------------
__global__ __launch_bounds__(256) void f32_to_bf16_x4(const float* __restrict__ in,
                                                      __hip_bfloat16* __restrict__ out) {
  int i = (blockIdx.x * 256 + threadIdx.x) * 4;
  float4 v = *(const float4*)(in + i);
  out[i + 0] = __float2bfloat16(v.x);
  out[i + 1] = __float2bfloat16(v.y);
  out[i + 2] = __float2bfloat16(v.z);
  out[i + 3] = __float2bfloat16(v.w);
}

__global__ __launch_bounds__(256) void prep_weights(
    const float* __restrict__ in_w, const float* __restrict__ delta_w,
    const float* __restrict__ Bp, const float* __restrict__ Cp,
    const float* __restrict__ out_w, const float* __restrict__ A_log,
    __hip_bfloat16* __restrict__ w_in, __hip_bfloat16* __restrict__ w_dbc,
    __hip_bfloat16* __restrict__ w_out, float* __restrict__ A2) {
  int i = blockIdx.x * 256 + threadIdx.x;
  if (i < 1536 * 768) { w_in[i] = __float2bfloat16(in_w[i]); return; }
  i -= 1536 * 768;
  if (i < 1024 * 768) {   // padded to 1024 rows for exact 256-tiling
    int row = i / 768, col = i - row * 768;
    float v;
    if (row < 768)      v = delta_w[row * 768 + col];
    else if (row < 784) v = Bp[(row - 768) * 768 + col];
    else if (row < 800) v = Cp[(row - 784) * 768 + col];
    else                v = 0.f;
    w_dbc[i] = __float2bfloat16(v);
    return;
  }
  i -= 1024 * 768;
  if (i < 768 * 768) { w_out[i] = __float2bfloat16(out_w[i]); return; }
  i -= 768 * 768;
  if (i < 768 * 16) A2[i] = -expf(A_log[i]) * 1.44269504088896f;  // A * log2(e)
}

// ---------------------------------------------------------------------------
// 256x256-tile 8-phase bf16 MFMA GEMM, C[M,N] = A[M,K] * B[N,K]^T
// BK=64, 512 threads = 8 waves (2M x 4N), per-wave 128x64 output.
// LDS 128KB: A/B double-buffered 32KB K-tiles, XOR-swizzled (byte ^= (row&7)<<4)
// via pre-swizzled global source (linear global_load_lds dest) + swizzled reads.
// Per K-tile: 4 quadrant phases {ds_read | stage-issue -> barrier -> setprio ->
// 16 MFMA -> setprio -> barrier}; single vmcnt(0) per K-tile, issued-early loads.
// MODE 0: in_proj -> bf16 x_in (col<768) / bf16 z (col>=768), +bias
// MODE 1: dbc     -> fp32 softplus(delta+bias) (col<768), fp32 B (768..783),
//                    fp32 C (784..799), skip >=800
// MODE 2: out_proj-> fp32 out + bias
// ---------------------------------------------------------------------------
template <int MODE>
__global__ __launch_bounds__(512) void gemm256(
    const __hip_bfloat16* __restrict__ Amat, const __hip_bfloat16* __restrict__ Bw,
    const float* __restrict__ bias, void* __restrict__ out0,
    void* __restrict__ out1, void* __restrict__ out2,
    const int K, const int gxn) {
  __shared__ char lds[131072];
  const int tid  = threadIdx.x;
  const int lane = tid & 63, wave = tid >> 6;
  const int wr = wave >> 2, wc = wave & 3;

  // T1: bijective XCD swizzle (gridDim.x divisible by 8 for all 3 GEMMs)
  const int nwg = gridDim.x;
  const int id  = blockIdx.x;
  const int swz = (id & 7) * (nwg >> 3) + (id >> 3);
  const int tm = swz / gxn, tn = swz % gxn;
  const int rowA0 = tm * 256, rowB0 = tn * 256;

  // --- staging source constants (inverse-swizzled global source) ---
  const int srow = tid >> 3;                                        // row within 64-row issue block
  const int scol = ((((tid & 7) << 4) ^ ((srow & 7) << 4)) >> 1);   // element col 0..63
  const __hip_bfloat16* gA = Amat + (size_t)(rowA0 + srow) * K + scol;
  const __hip_bfloat16* gB = Bw   + (size_t)(rowB0 + srow) * K + scol;
  const int ldst = tid << 4;  // linear LDS dst byte within an 8KB issue block

  // --- fragment read constants (swizzled ds_read address) ---
  const int frow = lane & 15;
  const int fq   = lane >> 4;                 // 0..3
  const int fswz = (lane & 7) << 4;
  const int pc0 = ((fq << 4)) ^ fswz;         // ksub=0 physical col byte
  const int pc1 = (64 | (fq << 4)) ^ fswz;    // ksub=1
  const int aro = (wr * 128 + frow) * 128;    // byte row offset in 32KB A tile
  const int bro = (wc * 64 + frow) * 128;

  f32x4 acc[2][2][4][2];  // [mh][nh][m][n]
#pragma unroll
  for (int mh = 0; mh < 2; ++mh)
#pragma unroll
    for (int nh = 0; nh < 2; ++nh)
#pragma unroll
      for (int m = 0; m < 4; ++m)
#pragma unroll
        for (int n = 0; n < 2; ++n) acc[mh][nh][m][n] = (f32x4){0.f, 0.f, 0.f, 0.f};

#define STAGE_A(buf, kt)                                                        \
  {                                                                             \
    const __hip_bfloat16* sp = gA + (size_t)(kt) * 64;                          \
    char* dp = lds + ((buf) << 15) + ldst;                                      \
    _Pragma("unroll") for (int ss = 0; ss < 4; ++ss)                            \
        gload_lds16(sp + (size_t)(ss * 64) * K, dp + ss * 8192);                \
  }
#define STAGE_B(buf, kt)                                                        \
  {                                                                             \
    const __hip_bfloat16* sp = gB + (size_t)(kt) * 64;                          \
    char* dp = lds + 65536 + ((buf) << 15) + ldst;                              \
    _Pragma("unroll") for (int ss = 0; ss < 4; ++ss)                            \
        gload_lds16(sp + (size_t)(ss * 64) * K, dp + ss * 8192);                \
  }

  short8 a[4][2], b[2][2];
#define LOADA(sAp, mh)                                                          \
  {                                                                             \
    _Pragma("unroll") for (int m = 0; m < 4; ++m) {                             \
      const char* p = (sAp) + aro + ((mh)*64 + m * 16) * 128;                   \
      a[m][0] = *(const short8*)(p + pc0);                                      \
      a[m][1] = *(const short8*)(p + pc1);                                      \
    }                                                                           \
  }
#define LOADB(sBp, nh)                                                          \
  {                                                                             \
    _Pragma("unroll") for (int n = 0; n < 2; ++n) {                             \
      const char* p = (sBp) + bro + ((nh)*32 + n * 16) * 128;                   \
      b[n][0] = *(const short8*)(p + pc0);                                      \
      b[n][1] = *(const short8*)(p + pc1);                                      \
    }                                                                           \
  }
#define MMA(mh, nh)                                                             \
  {                                                                             \
    __builtin_amdgcn_s_setprio(1);                                              \
    _Pragma("unroll") for (int m = 0; m < 4; ++m)                               \
    _Pragma("unroll") for (int n = 0; n < 2; ++n)                               \
    _Pragma("unroll") for (int ks = 0; ks < 2; ++ks)                            \
        acc[mh][nh][m][n] = __builtin_amdgcn_mfma_f32_16x16x32_bf16(            \
            a[m][ks], b[n][ks], acc[mh][nh][m][n], 0, 0, 0);                    \
    __builtin_amdgcn_s_setprio(0);                                              \
  }

  // prologue: stage K-tile 0 into buf 0
  STAGE_A(0, 0);
  STAGE_B(0, 0);
  asm volatile("s_waitcnt vmcnt(0)" ::: "memory");
  __builtin_amdgcn_s_barrier();

  const int NT = K >> 6;
  for (int kt = 0; kt < NT; ++kt) {
    const int cur = kt & 1, nxt = cur ^ 1;
    char* sA = lds + (cur << 15);
    char* sB = lds + 65536 + (cur << 15);
    const bool st = (kt + 1 < NT);
    // phase 0: quadrant (0,0); issue A-staging for next tile
    LOADA(sA, 0);
    LOADB(sB, 0);
    if (st) STAGE_A(nxt, kt + 1);
    __builtin_amdgcn_s_barrier();
    MMA(0, 0);
    __builtin_amdgcn_s_barrier();
    // phase 1: quadrant (0,1); issue B-staging for next tile
    LOADB(sB, 1);
    if (st) STAGE_B(nxt, kt + 1);
    __builtin_amdgcn_s_barrier();
    MMA(0, 1);
    __builtin_amdgcn_s_barrier();
    // phase 2: quadrant (1,1)
    LOADA(sA, 1);
    __builtin_amdgcn_s_barrier();
    MMA(1, 1);
    __builtin_amdgcn_s_barrier();
    // phase 3: quadrant (1,0)
    LOADB(sB, 0);
    __builtin_amdgcn_s_barrier();
    MMA(1, 0);
    asm volatile("s_waitcnt vmcnt(0)" ::: "memory");  // next tile fully staged (issued ~3 phases ago)
    __builtin_amdgcn_s_barrier();
  }

  // epilogue (C/D layout: col = lane&15, row = (lane>>4)*4 + i)
#pragma unroll
  for (int mh = 0; mh < 2; ++mh)
#pragma unroll
    for (int nh = 0; nh < 2; ++nh)
#pragma unroll
      for (int m = 0; m < 4; ++m)
#pragma unroll
        for (int n = 0; n < 2; ++n) {
          const int grow0 = rowA0 + wr * 128 + mh * 64 + m * 16 + fq * 4;
          const int gcol  = rowB0 + wc * 64 + nh * 32 + n * 16 + frow;
#pragma unroll
          for (int i = 0; i < 4; ++i) {
            const size_t grow = grow0 + i;
            float v = acc[mh][nh][m][n][i];
            if (MODE == 0) {
              v += bias[gcol];
              if (gcol < 768)
                ((__hip_bfloat16*)out0)[grow * 768 + gcol] = __float2bfloat16(v);
              else
                ((__hip_bfloat16*)out1)[grow * 768 + gcol - 768] = __float2bfloat16(v);
            } else if (MODE == 1) {
              if (gcol < 768) {
                v += bias[gcol];
                float sp = (v > 20.f) ? v : log1pf(expf(v));
                ((float*)out0)[grow * 768 + gcol] = sp;
              } else if (gcol < 784) {
                ((float*)out1)[grow * 16 + (gcol - 768)] = v;
              } else if (gcol < 800) {
                ((float*)out2)[grow * 16 + (gcol - 784)] = v;
              }
            } else {
              ((float*)out0)[grow * 768 + gcol] = v + bias[gcol];
            }
          }
        }
#undef STAGE_A
#undef STAGE_B
#undef LOADA
#undef LOADB
#undef MMA
}

// ---------------------------------------------------------------------------
// Depthwise conv1d (K=3, pad=1) + bias + SiLU.  x_in bf16 -> x_conv bf16
// ---------------------------------------------------------------------------
__global__ __launch_bounds__(256) void conv_silu(
    const __hip_bfloat16* __restrict__ xin, const float* __restrict__ conv_w,
    const float* __restrict__ conv_b, __hip_bfloat16* __restrict__ xc) {
  const int idx = blockIdx.x * 256 + threadIdx.x;  // over B*L*D
  const int d = idx % 768;
  const int t = (idx / 768) % SEQL;
  const float w0 = conv_w[d * 3], w1 = conv_w[d * 3 + 1], w2 = conv_w[d * 3 + 2];
  float acc = conv_b[d];
  float xm = (t > 0)        ? __bfloat162float(xin[idx - 768]) : 0.f;
  float x0 = __bfloat162float(xin[idx]);
  float xp = (t < SEQL - 1) ? __bfloat162float(xin[idx + 768]) : 0.f;
  acc += w0 * xm + w1 * x0 + w2 * xp;
  const float sig = 1.f / (1.f + __expf(-acc));
  xc[idx] = __float2bfloat16(acc * sig);
}

// ---------------------------------------------------------------------------
// Scan pass 1: per (b, d, chunk) local scan with h_in = 0
// ---------------------------------------------------------------------------
__global__ __launch_bounds__(256) void scan_pass1(
    const float* __restrict__ delta, const __hip_bfloat16* __restrict__ xconv,
    const float* __restrict__ Bsel, const float* __restrict__ A2,
    float* __restrict__ sumdt, float* __restrict__ Sbuf) {
  const int d = blockIdx.x * 256 + threadIdx.x;
  const int b = blockIdx.y, c = blockIdx.z;
  __shared__ float sB[TCHUNK * 16];
  ((float4*)sB)[threadIdx.x] =
      ((const float4*)(Bsel + ((size_t)b * SEQL + c * TCHUNK) * 16))[threadIdx.x];
  __syncthreads();

  float a2[16];
#pragma unroll
  for (int n = 0; n < 16; ++n) a2[n] = A2[d * 16 + n];
  float h[16] = {};
  float sdt = 0.f;
  const size_t base = ((size_t)b * SEQL + c * TCHUNK) * 768 + d;
  for (int t = 0; t < TCHUNK; ++t) {
    const float dt = delta[base + (size_t)t * 768];
    const float x = __bfloat162float(xconv[base + (size_t)t * 768]);
    sdt += dt;
    const float dtx = dt * x;
    const float* Br = &sB[t * 16];
#pragma unroll
    for (int n = 0; n < 16; ++n) {
      const float a = exp2f(dt * a2[n]);
      h[n] = fmaf(a, h[n], dtx * Br[n]);
    }
  }
  sumdt[((size_t)b * NCHUNK + c) * 768 + d] = sdt;
#pragma unroll
  for (int n = 0; n < 16; ++n)
    Sbuf[(((size_t)b * NCHUNK + c) * 16 + n) * 768 + d] = h[n];
}

// ---------------------------------------------------------------------------
// Scan pass 2: serial carry over chunks
// ---------------------------------------------------------------------------
__global__ __launch_bounds__(256) void scan_carry(
    const float* __restrict__ sumdt, const float* __restrict__ Sbuf,
    const float* __restrict__ A2, float* __restrict__ Hin) {
  const int idx = blockIdx.x * 256 + threadIdx.x;  // 0..6143
  const int b = idx / 768, d = idx - b * 768;
  float a2[16];
#pragma unroll
  for (int n = 0; n < 16; ++n) a2[n] = A2[d * 16 + n];
  float h[16] = {};
  for (int c = 0; c < NCHUNK; ++c) {
    const size_t hb = ((size_t)b * NCHUNK + c) * 16 * 768 + d;
#pragma unroll
    for (int n = 0; n < 16; ++n) Hin[hb + (size_t)n * 768] = h[n];
    const float sd = sumdt[((size_t)b * NCHUNK + c) * 768 + d];
#pragma unroll
    for (int n = 0; n < 16; ++n) {
      const float P = exp2f(sd * a2[n]);
      h[n] = fmaf(P, h[n], Sbuf[hb + (size_t)n * 768]);
    }
  }
}

// ---------------------------------------------------------------------------
// Scan pass 3: replay with correct h_in; fuse D-skip + silu(z) gating -> bf16
// ---------------------------------------------------------------------------
__global__ __launch_bounds__(256) void scan_pass3(
    const float* __restrict__ delta, const __hip_bfloat16* __restrict__ xconv,
    const __hip_bfloat16* __restrict__ zb, const float* __restrict__ Bsel,
    const float* __restrict__ Csel, const float* __restrict__ A2,
    const float* __restrict__ Hin, const float* __restrict__ Dp,
    __hip_bfloat16* __restrict__ yg) {
  const int d = blockIdx.x * 256 + threadIdx.x;
  const int b = blockIdx.y, c = blockIdx.z;
  __shared__ float sB[TCHUNK * 16], sC[TCHUNK * 16];
  {
    const size_t off = ((size_t)b * SEQL + c * TCHUNK) * 16;
    ((float4*)sB)[threadIdx.x] = ((const float4*)(Bsel + off))[threadIdx.x];
    ((float4*)sC)[threadIdx.x] = ((const float4*)(Csel + off))[threadIdx.x];
  }
  __syncthreads();

  float a2[16];
#pragma unroll
  for (int n = 0; n < 16; ++n) a2[n] = A2[d * 16 + n];
  float h[16];
  {
    const size_t hb = ((size_t)b * NCHUNK + c) * 16 * 768 + d;
#pragma unroll
    for (int n = 0; n < 16; ++n) h[n] = Hin[hb + (size_t)n * 768];
  }
  const float Dpd = Dp[d];
  const size_t base = ((size_t)b * SEQL + c * TCHUNK) * 768 + d;
  for (int t = 0; t < TCHUNK; ++t) {
    const float dt = delta[base + (size_t)t * 768];
    const float x = __bfloat162float(xconv[base + (size_t)t * 768]);
    const float dtx = dt * x;
    const float* Br = &sB[t * 16];
    const float* Cr = &sC[t * 16];
    float y = 0.f;
#pragma unroll
    for (int n = 0; n < 16; ++n) {
      const float a = exp2f(dt * a2[n]);
      h[n] = fmaf(a, h[n], dtx * Br[n]);
      y = fmaf(h[n], Cr[n], y);
    }
    const float z = __bfloat162float(zb[base + (size_t)t * 768]);
    const float sig = 1.f / (1.f + __expf(-z));
    const float out = (y + x * Dpd) * (z * sig);
    yg[base + (size_t)t * 768] = __float2bfloat16(out);
  }
}

// ---------------------------------------------------------------------------
// Launch
// ---------------------------------------------------------------------------
extern "C" void kernel_launch(void* const* d_in, const int* in_sizes, int n_in,
                              void* d_out, int out_size, void* d_ws, size_t ws_size,
                              hipStream_t stream) {
  const float* x       = (const float*)d_in[0];
  const float* A_log   = (const float*)d_in[1];
  const float* D_param = (const float*)d_in[2];
  const float* B_proj  = (const float*)d_in[3];
  const float* C_proj  = (const float*)d_in[4];
  const float* delta_w = (const float*)d_in[5];
  const float* delta_b = (const float*)d_in[6];
  const float* in_w    = (const float*)d_in[7];
  const float* in_b    = (const float*)d_in[8];
  const float* out_w   = (const float*)d_in[9];
  const float* out_b   = (const float*)d_in[10];
  const float* conv_w  = (const float*)d_in[11];
  const float* conv_b  = (const float*)d_in[12];

  char* ws = (char*)d_ws;
  __hip_bfloat16* xb      = (__hip_bfloat16*)(ws + 0);          // reused as yg after in_proj
  __hip_bfloat16* w_in_b  = (__hip_bfloat16*)(ws + 25165824);
  __hip_bfloat16* w_dbc_b = (__hip_bfloat16*)(ws + 27525120);   // 1024 x 768
  __hip_bfloat16* w_out_b = (__hip_bfloat16*)(ws + 29097984);
  float*          A2      = (float*)(ws + 30277632);
  __hip_bfloat16* xin_b   = (__hip_bfloat16*)(ws + 30326784);
  __hip_bfloat16* z_b     = (__hip_bfloat16*)(ws + 55492608);
  __hip_bfloat16* xconv_b = (__hip_bfloat16*)(ws + 80658432);
  float*          delta_f = (float*)(ws + 105824256);
  float*          Bsel    = (float*)(ws + 156155904);
  float*          Csel    = (float*)(ws + 157204480);
  float*          sumdt   = (float*)(ws + 158253056);
  float*          Sbuf    = (float*)(ws + 159039488);
  float*          Hin     = (float*)(ws + 171622400);
  __hip_bfloat16* yg      = xb;  // x (bf16) dead after in_proj GEMM

  const int BLD = BATCH * SEQL * D_MODEL;  // 12,582,912

  // 1. x -> bf16
  f32_to_bf16_x4<<<BLD / 4 / 256, 256, 0, stream>>>(x, xb);
  // 2. weights -> bf16 (+ A2 table); dbc padded to 1024 rows
  prep_weights<<<(1536 * 768 + 1024 * 768 + 768 * 768 + 768 * 16) / 256, 256, 0, stream>>>(
      in_w, delta_w, B_proj, C_proj, out_w, A_log, w_in_b, w_dbc_b, w_out_b, A2);
  // 3. in_proj GEMM [16384,1536] : 64 x 6 tiles
  gemm256<0><<<384, 512, 0, stream>>>(xb, w_in_b, in_b, xin_b, z_b, nullptr, 768, 6);
  // 4. depthwise conv + silu
  conv_silu<<<BLD / 256, 256, 0, stream>>>(xin_b, conv_w, conv_b, xconv_b);
  // 5. delta/B/C GEMM [16384,1024] : 64 x 4 tiles
  gemm256<1><<<256, 512, 0, stream>>>(xconv_b, w_dbc_b, delta_b, delta_f, Bsel, Csel, 768, 4);
  // 6-8. chunked scan
  scan_pass1<<<dim3(3, BATCH, NCHUNK), 256, 0, stream>>>(delta_f, xconv_b, Bsel, A2, sumdt, Sbuf);
  scan_carry<<<24, 256, 0, stream>>>(sumdt, Sbuf, A2, Hin);
  scan_pass3<<<dim3(3, BATCH, NCHUNK), 256, 0, stream>>>(delta_f, xconv_b, z_b, Bsel, Csel, A2,
                                                         Hin, D_param, yg);
  // 9. out_proj GEMM [16384,768] -> d_out : 64 x 3 tiles
  gemm256<2><<<192, 512, 0, stream>>>(yg, w_out_b, out_b, (float*)d_out, nullptr, nullptr, 768, 3);
}

// Round 3
// 383.888 us; speedup vs baseline: 1.1097x; 1.0393x over previous
//
#include <hip/hip_runtime.h>
#include <hip/hip_bf16.h>

// Problem constants
#define D_MODEL 768
#define SEQL    2048
#define BATCH   8
#define NSTATE  16
#define NCHUNK  32
#define TCHUNK  64   // SEQL / NCHUNK

typedef __attribute__((ext_vector_type(8))) short short8;
typedef __attribute__((ext_vector_type(4))) float f32x4;

typedef const __attribute__((address_space(1))) unsigned int gas1_t;
typedef __attribute__((address_space(3))) unsigned int las3_t;

__device__ __forceinline__ void gload_lds16(const void* g, void* l) {
  __builtin_amdgcn_global_load_lds((gas1_t*)g, (las3_t*)l, 16, 0, 0);
}

// ---------------------------------------------------------------------------
// Merged prep: x -> bf16 (x4 per thread), weights -> bf16, A2 table.
// threads: 3145728 (x) + 1179648 (in_w) + 688128 (dbc) + 589824 (out_w) + 12288 (A2)
//        = 5615616 = 21936 * 256
// ---------------------------------------------------------------------------
__global__ __launch_bounds__(256) void prep_all(
    const float* __restrict__ x, const float* __restrict__ in_w,
    const float* __restrict__ delta_w, const float* __restrict__ Bp,
    const float* __restrict__ Cp, const float* __restrict__ out_w,
    const float* __restrict__ A_log,
    __hip_bfloat16* __restrict__ xb, __hip_bfloat16* __restrict__ w_in,
    __hip_bfloat16* __restrict__ w_dbc, __hip_bfloat16* __restrict__ w_out,
    float* __restrict__ A2) {
  int i = blockIdx.x * 256 + threadIdx.x;
  if (i < 3145728) {
    int j = i * 4;
    float4 v = *(const float4*)(x + j);
    xb[j + 0] = __float2bfloat16(v.x);
    xb[j + 1] = __float2bfloat16(v.y);
    xb[j + 2] = __float2bfloat16(v.z);
    xb[j + 3] = __float2bfloat16(v.w);
    return;
  }
  i -= 3145728;
  if (i < 1536 * 768) { w_in[i] = __float2bfloat16(in_w[i]); return; }
  i -= 1536 * 768;
  if (i < 896 * 768) {   // 896 rows = 768 delta + 16 B + 16 C + 96 pad
    int row = i / 768, col = i - row * 768;
    float v;
    if (row < 768)      v = delta_w[row * 768 + col];
    else if (row < 784) v = Bp[(row - 768) * 768 + col];
    else if (row < 800) v = Cp[(row - 784) * 768 + col];
    else                v = 0.f;
    w_dbc[i] = __float2bfloat16(v);
    return;
  }
  i -= 896 * 768;
  if (i < 768 * 768) { w_out[i] = __float2bfloat16(out_w[i]); return; }
  i -= 768 * 768;
  A2[i] = -expf(A_log[i]) * 1.44269504088896f;  // A * log2(e)
}

// ---------------------------------------------------------------------------
// 128x128-tile bf16 MFMA GEMM, C[M,N] = A[M,K] * B[N,K]^T
// BK=64, 256 threads = 4 waves (2M x 2N), per-wave 64x64 output.
// LDS 64KB (2 blocks/CU): A/B double-buffered 16KB K-tiles, XOR-swizzled
// (byte ^= (row&7)<<4) via pre-swizzled global source + swizzled ds_reads.
// 2 phases/K-tile; staging issued phase 0, single vmcnt(0) at end of phase 1.
// MODE 0: in_proj -> bf16 x_in (col<768) / bf16 z (col>=768), +bias
// MODE 1: dbc     -> bf16 softplus(delta+bias) (col<768), f32 B (768..783),
//                    f32 C (784..799), skip >=800
// MODE 2: out_proj-> f32 out + bias
// ---------------------------------------------------------------------------
template <int MODE>
__global__ __launch_bounds__(256, 2) void gemm128(
    const __hip_bfloat16* __restrict__ Amat, const __hip_bfloat16* __restrict__ Bw,
    const float* __restrict__ bias, void* __restrict__ out0,
    void* __restrict__ out1, void* __restrict__ out2,
    const int K, const int gxn) {
  __shared__ char lds[65536];
  const int tid  = threadIdx.x;
  const int lane = tid & 63, wave = tid >> 6;
  const int wr = wave >> 1, wc = wave & 1;

  // T1: bijective XCD swizzle (gridDim.x divisible by 8 for all 3 GEMMs)
  const int nwg = gridDim.x, id = blockIdx.x;
  const int swz = (id & 7) * (nwg >> 3) + (id >> 3);
  const int tm = swz / gxn, tn = swz - tm * gxn;
  const int rowA0 = tm * 128, rowB0 = tn * 128;

  // staging source (inverse-swizzled global source, linear LDS dest)
  const int srow = tid >> 3;                                        // 0..31
  const int scol = ((((tid & 7) << 4) ^ ((srow & 7) << 4)) >> 1);   // elem col
  const __hip_bfloat16* gA = Amat + (size_t)(rowA0 + srow) * K + scol;
  const __hip_bfloat16* gB = Bw   + (size_t)(rowB0 + srow) * K + scol;
  const int ldst = tid << 4;

  // fragment reads (swizzled ds_read address)
  const int frow = lane & 15, fq = lane >> 4;
  const int fswz = (frow & 7) << 4;
  const int pc0 = (fq << 4) ^ fswz;
  const int pc1 = (64 | (fq << 4)) ^ fswz;
  const int aro = (wr * 64 + frow) << 7;   // byte row offset, 128B rows
  const int bro = (wc * 64 + frow) << 7;

  f32x4 acc[4][4];
#pragma unroll
  for (int m = 0; m < 4; ++m)
#pragma unroll
    for (int n = 0; n < 4; ++n) acc[m][n] = (f32x4){0.f, 0.f, 0.f, 0.f};

#define SA(buf) (lds + ((buf) << 15))
#define SB(buf) (lds + ((buf) << 15) + 16384)
#define STAGE(buf, kt)                                                          \
  {                                                                             \
    const __hip_bfloat16* spA = gA + (size_t)(kt) * 64;                         \
    const __hip_bfloat16* spB = gB + (size_t)(kt) * 64;                         \
    char* dA = SA(buf) + ldst;                                                  \
    char* dB = SB(buf) + ldst;                                                  \
    _Pragma("unroll") for (int ss = 0; ss < 4; ++ss)                            \
        gload_lds16(spA + (size_t)(ss * 32) * K, dA + ss * 4096);               \
    _Pragma("unroll") for (int ss = 0; ss < 4; ++ss)                            \
        gload_lds16(spB + (size_t)(ss * 32) * K, dB + ss * 4096);               \
  }

  short8 a[4][2], b[2][2];
#define LOADA(sAp)                                                              \
  {                                                                             \
    _Pragma("unroll") for (int m = 0; m < 4; ++m) {                             \
      const char* p = (sAp) + aro + ((m * 16) << 7);                            \
      a[m][0] = *(const short8*)(p + pc0);                                      \
      a[m][1] = *(const short8*)(p + pc1);                                      \
    }                                                                           \
  }
#define LOADB(sBp, nh)                                                          \
  {                                                                             \
    _Pragma("unroll") for (int n = 0; n < 2; ++n) {                             \
      const char* p = (sBp) + bro + ((((nh)*2 + n) * 16) << 7);                 \
      b[n][0] = *(const short8*)(p + pc0);                                      \
      b[n][1] = *(const short8*)(p + pc1);                                      \
    }                                                                           \
  }
#define MMA(nh)                                                                 \
  {                                                                             \
    __builtin_amdgcn_s_setprio(1);                                              \
    _Pragma("unroll") for (int m = 0; m < 4; ++m)                               \
    _Pragma("unroll") for (int n = 0; n < 2; ++n)                               \
    _Pragma("unroll") for (int ks = 0; ks < 2; ++ks)                            \
        acc[m][(nh)*2 + n] = __builtin_amdgcn_mfma_f32_16x16x32_bf16(           \
            a[m][ks], b[n][ks], acc[m][(nh)*2 + n], 0, 0, 0);                   \
    __builtin_amdgcn_s_setprio(0);                                              \
  }

  // prologue: stage K-tile 0 into buf 0
  STAGE(0, 0);
  asm volatile("s_waitcnt vmcnt(0)" ::: "memory");
  __builtin_amdgcn_s_barrier();

  const int NT = K >> 6;
  for (int kt = 0; kt < NT; ++kt) {
    const int cur = kt & 1, nxt = cur ^ 1;
    const bool st = (kt + 1 < NT);
    // phase 0
    LOADA(SA(cur));
    LOADB(SB(cur), 0);
    if (st) STAGE(nxt, kt + 1);
    __builtin_amdgcn_s_barrier();
    MMA(0);
    __builtin_amdgcn_s_barrier();
    // phase 1
    LOADB(SB(cur), 1);
    __builtin_amdgcn_s_barrier();
    MMA(1);
    asm volatile("s_waitcnt vmcnt(0)" ::: "memory");  // staged ~2 phases ago
    __builtin_amdgcn_s_barrier();
  }

  // epilogue (C/D layout: col = lane&15, row = (lane>>4)*4 + i)
#pragma unroll
  for (int m = 0; m < 4; ++m) {
    const int grow0 = rowA0 + wr * 64 + m * 16 + fq * 4;
#pragma unroll
    for (int n = 0; n < 4; ++n) {
      const int gcol = rowB0 + wc * 64 + n * 16 + frow;
#pragma unroll
      for (int i = 0; i < 4; ++i) {
        const size_t grow = grow0 + i;
        float v = acc[m][n][i];
        if (MODE == 0) {
          v += bias[gcol];
          if (gcol < 768)
            ((__hip_bfloat16*)out0)[grow * 768 + gcol] = __float2bfloat16(v);
          else
            ((__hip_bfloat16*)out1)[grow * 768 + gcol - 768] = __float2bfloat16(v);
        } else if (MODE == 1) {
          if (gcol < 768) {
            v += bias[gcol];
            float sp = (v > 20.f) ? v : log1pf(expf(v));
            ((__hip_bfloat16*)out0)[grow * 768 + gcol] = __float2bfloat16(sp);
          } else if (gcol < 784) {
            ((float*)out1)[grow * 16 + (gcol - 768)] = v;
          } else if (gcol < 800) {
            ((float*)out2)[grow * 16 + (gcol - 784)] = v;
          }
        } else {
          ((float*)out0)[grow * 768 + gcol] = v + bias[gcol];
        }
      }
    }
  }
#undef SA
#undef SB
#undef STAGE
#undef LOADA
#undef LOADB
#undef MMA
}

// ---------------------------------------------------------------------------
// Depthwise conv1d (K=3, pad=1) + bias + SiLU.  x_in bf16 -> x_conv bf16
// ---------------------------------------------------------------------------
__global__ __launch_bounds__(256) void conv_silu(
    const __hip_bfloat16* __restrict__ xin, const float* __restrict__ conv_w,
    const float* __restrict__ conv_b, __hip_bfloat16* __restrict__ xc) {
  const int idx = blockIdx.x * 256 + threadIdx.x;  // over B*L*D
  const int d = idx % 768;
  const int t = (idx / 768) % SEQL;
  const float w0 = conv_w[d * 3], w1 = conv_w[d * 3 + 1], w2 = conv_w[d * 3 + 2];
  float acc = conv_b[d];
  float xm = (t > 0)        ? __bfloat162float(xin[idx - 768]) : 0.f;
  float x0 = __bfloat162float(xin[idx]);
  float xp = (t < SEQL - 1) ? __bfloat162float(xin[idx + 768]) : 0.f;
  acc += w0 * xm + w1 * x0 + w2 * xp;
  const float sig = 1.f / (1.f + __expf(-acc));
  xc[idx] = __float2bfloat16(acc * sig);
}

// ---------------------------------------------------------------------------
// Scan pass 1: per (b, d, chunk) local scan with h_in = 0
// ---------------------------------------------------------------------------
__global__ __launch_bounds__(256) void scan_pass1(
    const __hip_bfloat16* __restrict__ delta, const __hip_bfloat16* __restrict__ xconv,
    const float* __restrict__ Bsel, const float* __restrict__ A2,
    float* __restrict__ sumdt, float* __restrict__ Sbuf) {
  const int d = blockIdx.x * 256 + threadIdx.x;
  const int b = blockIdx.y, c = blockIdx.z;
  __shared__ float sB[TCHUNK * 16];
  ((float4*)sB)[threadIdx.x] =
      ((const float4*)(Bsel + ((size_t)b * SEQL + c * TCHUNK) * 16))[threadIdx.x];
  __syncthreads();

  float a2[16];
#pragma unroll
  for (int n = 0; n < 16; ++n) a2[n] = A2[d * 16 + n];
  float h[16] = {};
  float sdt = 0.f;
  const size_t base = ((size_t)b * SEQL + c * TCHUNK) * 768 + d;
  for (int t = 0; t < TCHUNK; ++t) {
    const float dt = __bfloat162float(delta[base + (size_t)t * 768]);
    const float x = __bfloat162float(xconv[base + (size_t)t * 768]);
    sdt += dt;
    const float dtx = dt * x;
    const float* Br = &sB[t * 16];
#pragma unroll
    for (int n = 0; n < 16; ++n) {
      const float a = exp2f(dt * a2[n]);
      h[n] = fmaf(a, h[n], dtx * Br[n]);
    }
  }
  sumdt[((size_t)b * NCHUNK + c) * 768 + d] = sdt;
#pragma unroll
  for (int n = 0; n < 16; ++n)
    Sbuf[(((size_t)b * NCHUNK + c) * 16 + n) * 768 + d] = h[n];
}

// ---------------------------------------------------------------------------
// Scan pass 2: serial carry over chunks, one thread per (b, n, d) chain.
// 98304 threads = 384 blocks.
// ---------------------------------------------------------------------------
__global__ __launch_bounds__(256) void scan_carry(
    const float* __restrict__ sumdt, const float* __restrict__ Sbuf,
    const float* __restrict__ A2, float* __restrict__ Hin) {
  const int idx = blockIdx.x * 256 + threadIdx.x;  // 0..98303
  const int d = idx % 768;
  const int n = (idx / 768) & 15;
  const int b = idx / (768 * 16);
  const float a2 = A2[d * 16 + n];
  float h = 0.f;
  for (int c = 0; c < NCHUNK; ++c) {
    const size_t hb = (((size_t)(b * NCHUNK + c)) * 16 + n) * 768 + d;
    Hin[hb] = h;
    const float sd = sumdt[(b * NCHUNK + c) * 768 + d];
    h = fmaf(exp2f(sd * a2), h, Sbuf[hb]);
  }
}

// ---------------------------------------------------------------------------
// Scan pass 3: replay with correct h_in; fuse D-skip + silu(z) gating -> bf16
// ---------------------------------------------------------------------------
__global__ __launch_bounds__(256) void scan_pass3(
    const __hip_bfloat16* __restrict__ delta, const __hip_bfloat16* __restrict__ xconv,
    const __hip_bfloat16* __restrict__ zb, const float* __restrict__ Bsel,
    const float* __restrict__ Csel, const float* __restrict__ A2,
    const float* __restrict__ Hin, const float* __restrict__ Dp,
    __hip_bfloat16* __restrict__ yg) {
  const int d = blockIdx.x * 256 + threadIdx.x;
  const int b = blockIdx.y, c = blockIdx.z;
  __shared__ float sB[TCHUNK * 16], sC[TCHUNK * 16];
  {
    const size_t off = ((size_t)b * SEQL + c * TCHUNK) * 16;
    ((float4*)sB)[threadIdx.x] = ((const float4*)(Bsel + off))[threadIdx.x];
    ((float4*)sC)[threadIdx.x] = ((const float4*)(Csel + off))[threadIdx.x];
  }
  __syncthreads();

  float a2[16];
#pragma unroll
  for (int n = 0; n < 16; ++n) a2[n] = A2[d * 16 + n];
  float h[16];
  {
    const size_t hb = ((size_t)b * NCHUNK + c) * 16 * 768 + d;
#pragma unroll
    for (int n = 0; n < 16; ++n) h[n] = Hin[hb + (size_t)n * 768];
  }
  const float Dpd = Dp[d];
  const size_t base = ((size_t)b * SEQL + c * TCHUNK) * 768 + d;
  for (int t = 0; t < TCHUNK; ++t) {
    const float dt = __bfloat162float(delta[base + (size_t)t * 768]);
    const float x = __bfloat162float(xconv[base + (size_t)t * 768]);
    const float dtx = dt * x;
    const float* Br = &sB[t * 16];
    const float* Cr = &sC[t * 16];
    float y = 0.f;
#pragma unroll
    for (int n = 0; n < 16; ++n) {
      const float a = exp2f(dt * a2[n]);
      h[n] = fmaf(a, h[n], dtx * Br[n]);
      y = fmaf(h[n], Cr[n], y);
    }
    const float z = __bfloat162float(zb[base + (size_t)t * 768]);
    const float sig = 1.f / (1.f + __expf(-z));
    const float out = (y + x * Dpd) * (z * sig);
    yg[base + (size_t)t * 768] = __float2bfloat16(out);
  }
}

// ---------------------------------------------------------------------------
// Launch
// ---------------------------------------------------------------------------
extern "C" void kernel_launch(void* const* d_in, const int* in_sizes, int n_in,
                              void* d_out, int out_size, void* d_ws, size_t ws_size,
                              hipStream_t stream) {
  const float* x       = (const float*)d_in[0];
  const float* A_log   = (const float*)d_in[1];
  const float* D_param = (const float*)d_in[2];
  const float* B_proj  = (const float*)d_in[3];
  const float* C_proj  = (const float*)d_in[4];
  const float* delta_w = (const float*)d_in[5];
  const float* delta_b = (const float*)d_in[6];
  const float* in_w    = (const float*)d_in[7];
  const float* in_b    = (const float*)d_in[8];
  const float* out_w   = (const float*)d_in[9];
  const float* out_b   = (const float*)d_in[10];
  const float* conv_w  = (const float*)d_in[11];
  const float* conv_b  = (const float*)d_in[12];

  char* ws = (char*)d_ws;
  __hip_bfloat16* xb       = (__hip_bfloat16*)(ws + 0);          // reused as yg later
  __hip_bfloat16* w_in_b   = (__hip_bfloat16*)(ws + 25165824);
  __hip_bfloat16* w_dbc_b  = (__hip_bfloat16*)(ws + 27525120);   // 896 x 768
  __hip_bfloat16* w_out_b  = (__hip_bfloat16*)(ws + 28901376);
  float*          A2       = (float*)(ws + 30081024);
  __hip_bfloat16* xin_b    = (__hip_bfloat16*)(ws + 30130176);
  __hip_bfloat16* z_b      = (__hip_bfloat16*)(ws + 55296000);
  __hip_bfloat16* xconv_b  = (__hip_bfloat16*)(ws + 80461824);
  __hip_bfloat16* delta_bf = (__hip_bfloat16*)(ws + 105627648);
  float*          Bsel     = (float*)(ws + 130793472);
  float*          Csel     = (float*)(ws + 131842048);
  float*          sumdt    = (float*)(ws + 132890624);
  float*          Sbuf     = (float*)(ws + 133677056);
  float*          Hin      = (float*)(ws + 146259968);
  __hip_bfloat16* yg       = xb;  // x (bf16) dead after in_proj GEMM

  const int BLD = BATCH * SEQL * D_MODEL;  // 12,582,912

  // 1. prep: x->bf16, weights->bf16, A2
  prep_all<<<21936, 256, 0, stream>>>(x, in_w, delta_w, B_proj, C_proj, out_w, A_log,
                                      xb, w_in_b, w_dbc_b, w_out_b, A2);
  // 2. in_proj GEMM [16384,1536] : 128 x 12 tiles
  gemm128<0><<<1536, 256, 0, stream>>>(xb, w_in_b, in_b, xin_b, z_b, nullptr, 768, 12);
  // 3. depthwise conv + silu
  conv_silu<<<BLD / 256, 256, 0, stream>>>(xin_b, conv_w, conv_b, xconv_b);
  // 4. delta/B/C GEMM [16384,896] : 128 x 7 tiles
  gemm128<1><<<896, 256, 0, stream>>>(xconv_b, w_dbc_b, delta_b, delta_bf, Bsel, Csel, 768, 7);
  // 5-7. chunked scan
  scan_pass1<<<dim3(3, BATCH, NCHUNK), 256, 0, stream>>>(delta_bf, xconv_b, Bsel, A2, sumdt, Sbuf);
  scan_carry<<<384, 256, 0, stream>>>(sumdt, Sbuf, A2, Hin);
  scan_pass3<<<dim3(3, BATCH, NCHUNK), 256, 0, stream>>>(delta_bf, xconv_b, z_b, Bsel, Csel, A2,
                                                         Hin, D_param, yg);
  // 8. out_proj GEMM [16384,768] -> d_out : 128 x 6 tiles
  gemm128<2><<<768, 256, 0, stream>>>(yg, w_out_b, out_b, (float*)d_out, nullptr, nullptr, 768, 6);
}

// Round 4
// 363.762 us; speedup vs baseline: 1.1711x; 1.0553x over previous
//
#include <hip/hip_runtime.h>
#include <hip/hip_bf16.h>

// Problem constants
#define D_MODEL 768
#define SEQL    2048
#define BATCH   8
#define NSTATE  16
#define NCHUNK  32
#define TCHUNK  64   // SEQL / NCHUNK

typedef __attribute__((ext_vector_type(8))) short short8;
typedef __attribute__((ext_vector_type(4))) float f32x4;

typedef const __attribute__((address_space(1))) unsigned int gas1_t;
typedef __attribute__((address_space(3))) unsigned int las3_t;

__device__ __forceinline__ void gload_lds16(const void* g, void* l) {
  __builtin_amdgcn_global_load_lds((gas1_t*)g, (las3_t*)l, 16, 0, 0);
}

// ---------------------------------------------------------------------------
// Merged prep: x -> bf16 (x4/thread), weights -> bf16 (dbc padded to 1024
// rows), A2 table.  threads = 3145728 + 1179648 + 786432 + 589824 + 12288
//                           = 5713920 = 22320 * 256
// ---------------------------------------------------------------------------
__global__ __launch_bounds__(256) void prep_all(
    const float* __restrict__ x, const float* __restrict__ in_w,
    const float* __restrict__ delta_w, const float* __restrict__ Bp,
    const float* __restrict__ Cp, const float* __restrict__ out_w,
    const float* __restrict__ A_log,
    __hip_bfloat16* __restrict__ xb, __hip_bfloat16* __restrict__ w_in,
    __hip_bfloat16* __restrict__ w_dbc, __hip_bfloat16* __restrict__ w_out,
    float* __restrict__ A2) {
  int i = blockIdx.x * 256 + threadIdx.x;
  if (i < 3145728) {
    int j = i * 4;
    float4 v = *(const float4*)(x + j);
    xb[j + 0] = __float2bfloat16(v.x);
    xb[j + 1] = __float2bfloat16(v.y);
    xb[j + 2] = __float2bfloat16(v.z);
    xb[j + 3] = __float2bfloat16(v.w);
    return;
  }
  i -= 3145728;
  if (i < 1536 * 768) { w_in[i] = __float2bfloat16(in_w[i]); return; }
  i -= 1536 * 768;
  if (i < 1024 * 768) {   // 1024 rows = 768 delta + 16 B + 16 C + 224 pad
    int row = i / 768, col = i - row * 768;
    float v;
    if (row < 768)      v = delta_w[row * 768 + col];
    else if (row < 784) v = Bp[(row - 768) * 768 + col];
    else if (row < 800) v = Cp[(row - 784) * 768 + col];
    else                v = 0.f;
    w_dbc[i] = __float2bfloat16(v);
    return;
  }
  i -= 1024 * 768;
  if (i < 768 * 768) { w_out[i] = __float2bfloat16(out_w[i]); return; }
  i -= 768 * 768;
  A2[i] = -expf(A_log[i]) * 1.44269504088896f;  // A * log2(e)
}

// ---------------------------------------------------------------------------
// 256x256-tile bf16 MFMA GEMM, C[M,N] = A[M,K] * B[N,K]^T, K=768.
// 512 threads = 8 waves (2M x 4N). BK=64; 4 quadrant phases per K-tile,
// half-tile-granular staging with counted vmcnt(4) (never drains to 0 in the
// main loop; last K-tile peeled with 4/2/0).  LDS 128KB: 2 dbuf x {A,B} x
// 2 halves x 16KB, XOR-swizzled (byte ^= (row&7)<<4) via pre-swizzled global
// source + swizzled ds_reads (verified 0 bank conflicts in R3).
// MODE 0: in_proj -> bf16 x_in (col<768) / bf16 z (col>=768), +bias
// MODE 1: dbc     -> bf16 softplus(delta+bias) (col<768), f32 B (768..783),
//                    f32 C (784..799), skip >=800
// MODE 2: out_proj-> f32 out + bias
// ---------------------------------------------------------------------------
template <int MODE>
__global__ __launch_bounds__(512, 2) void gemm256(
    const __hip_bfloat16* __restrict__ Amat, const __hip_bfloat16* __restrict__ Bw,
    const float* __restrict__ bias, void* __restrict__ out0,
    void* __restrict__ out1, void* __restrict__ out2, const int gxn) {
  constexpr int K = 768;
  __shared__ char lds[131072];
  const int tid  = threadIdx.x;
  const int lane = tid & 63, wave = tid >> 6;
  const int wr = wave >> 2, wc = wave & 3;   // 2M x 4N

  // T1: bijective XCD swizzle (gridDim.x divisible by 8 for all 3 GEMMs)
  const int nwg = gridDim.x, id = blockIdx.x;
  const int swz = (id & 7) * (nwg >> 3) + (id >> 3);
  const int tm = swz / gxn, tn = swz - tm * gxn;
  const int rowA0 = tm * 256, rowB0 = tn * 256;

  // staging source (inverse-swizzled global source, linear LDS dest)
  // per half-tile (128 rows x 64 K): 2 loads/thread at rows srow0, srow0+64
  const int srow0 = tid >> 3;                                  // 0..63
  const int scol  = (((tid & 7) ^ (srow0 & 7)) << 3);          // elem col
  const __hip_bfloat16* gA = Amat + (size_t)(rowA0 + srow0) * K + scol;
  const __hip_bfloat16* gB = Bw   + (size_t)(rowB0 + srow0) * K + scol;
  const int ldst = tid << 4;

  // fragment reads (swizzled ds_read address)
  const int frow = lane & 15, fq = lane >> 4;
  const int fswz = (frow & 7) << 4;
  const int pc0 = (fq << 4) ^ fswz;
  const int pc1 = (64 | (fq << 4)) ^ fswz;
  const int aro = (wr * 64 + frow) << 7;   // byte row offset within A-half
  const int bro = (wc * 32 + frow) << 7;   // byte row offset within B-half

  f32x4 acc[2][2][4][2];
#pragma unroll
  for (int mh = 0; mh < 2; ++mh)
#pragma unroll
    for (int nh = 0; nh < 2; ++nh)
#pragma unroll
      for (int m = 0; m < 4; ++m)
#pragma unroll
        for (int n = 0; n < 2; ++n) acc[mh][nh][m][n] = (f32x4){0.f, 0.f, 0.f, 0.f};

  // LDS bases: A[d][h] = d*65536 + h*16384 ; B[d][h] = d*65536 + 32768 + h*16384
#define STAGE_AH(d, h, kt)                                                      \
  {                                                                             \
    const __hip_bfloat16* s0 = gA + (size_t)((h)*128) * K + (kt)*64;            \
    char* d0 = lds + ((d) << 16) + ((h) << 14) + ldst;                          \
    gload_lds16(s0, d0);                                                        \
    gload_lds16(s0 + (size_t)64 * K, d0 + 8192);                                \
  }
#define STAGE_BH(d, h, kt)                                                      \
  {                                                                             \
    const __hip_bfloat16* s0 = gB + (size_t)((h)*128) * K + (kt)*64;            \
    char* d0 = lds + ((d) << 16) + 32768 + ((h) << 14) + ldst;                  \
    gload_lds16(s0, d0);                                                        \
    gload_lds16(s0 + (size_t)64 * K, d0 + 8192);                                \
  }

  short8 a[4][2], b[2][2];
#define LOADA(d, mh)                                                            \
  {                                                                             \
    const char* base = lds + ((d) << 16) + ((mh) << 14) + aro;                  \
    _Pragma("unroll") for (int m = 0; m < 4; ++m) {                             \
      const char* p = base + ((m * 16) << 7);                                   \
      a[m][0] = *(const short8*)(p + pc0);                                      \
      a[m][1] = *(const short8*)(p + pc1);                                      \
    }                                                                           \
  }
#define LOADB(d, nh)                                                            \
  {                                                                             \
    const char* base = lds + ((d) << 16) + 32768 + ((nh) << 14) + bro;          \
    _Pragma("unroll") for (int n = 0; n < 2; ++n) {                             \
      const char* p = base + ((n * 16) << 7);                                   \
      b[n][0] = *(const short8*)(p + pc0);                                      \
      b[n][1] = *(const short8*)(p + pc1);                                      \
    }                                                                           \
  }
#define MMA(mh, nh)                                                             \
  {                                                                             \
    __builtin_amdgcn_s_setprio(1);                                              \
    _Pragma("unroll") for (int m = 0; m < 4; ++m)                               \
    _Pragma("unroll") for (int n = 0; n < 2; ++n)                               \
    _Pragma("unroll") for (int ks = 0; ks < 2; ++ks)                            \
        acc[mh][nh][m][n] = __builtin_amdgcn_mfma_f32_16x16x32_bf16(            \
            a[m][ks], b[n][ks], acc[mh][nh][m][n], 0, 0, 0);                    \
    __builtin_amdgcn_s_setprio(0);                                              \
  }
#define VMW(n) asm volatile("s_waitcnt vmcnt(" #n ")" ::: "memory")

  // prologue: stage tile 0 in consumption order A0,B0,B1,A1 (8 loads)
  STAGE_AH(0, 0, 0);
  STAGE_BH(0, 0, 0);
  STAGE_BH(0, 1, 0);
  STAGE_AH(0, 1, 0);

  constexpr int NT = K / 64;  // 12
  for (int kt = 0; kt < NT - 1; ++kt) {
    const int cur = kt & 1, nxt = cur ^ 1;
    // phase 0: quadrant (0,0)
    VMW(4);
    __builtin_amdgcn_s_barrier();
    LOADA(cur, 0);
    LOADB(cur, 0);
    STAGE_AH(nxt, 0, kt + 1);
    MMA(0, 0);
    // phase 1: quadrant (0,1)
    VMW(4);
    __builtin_amdgcn_s_barrier();
    LOADB(cur, 1);
    STAGE_BH(nxt, 0, kt + 1);
    MMA(0, 1);
    // phase 2: quadrant (1,1)
    VMW(4);
    __builtin_amdgcn_s_barrier();
    LOADA(cur, 1);
    STAGE_BH(nxt, 1, kt + 1);
    MMA(1, 1);
    // phase 3: quadrant (1,0)
    __builtin_amdgcn_s_barrier();
    LOADB(cur, 0);
    STAGE_AH(nxt, 1, kt + 1);
    MMA(1, 0);
  }
  {  // peeled last K-tile (no staging; tightening waits 4/2/0)
    const int cur = (NT - 1) & 1;
    VMW(4);
    __builtin_amdgcn_s_barrier();
    LOADA(cur, 0);
    LOADB(cur, 0);
    MMA(0, 0);
    VMW(2);
    __builtin_amdgcn_s_barrier();
    LOADB(cur, 1);
    MMA(0, 1);
    VMW(0);
    __builtin_amdgcn_s_barrier();
    LOADA(cur, 1);
    MMA(1, 1);
    __builtin_amdgcn_s_barrier();
    LOADB(cur, 0);
    MMA(1, 0);
  }

  // epilogue (C/D layout: col = lane&15, row = (lane>>4)*4 + i)
#pragma unroll
  for (int mh = 0; mh < 2; ++mh)
#pragma unroll
    for (int nh = 0; nh < 2; ++nh)
#pragma unroll
      for (int m = 0; m < 4; ++m) {
        const int grow0 = rowA0 + mh * 128 + wr * 64 + m * 16 + fq * 4;
#pragma unroll
        for (int n = 0; n < 2; ++n) {
          const int gcol = rowB0 + nh * 128 + wc * 32 + n * 16 + frow;
#pragma unroll
          for (int i = 0; i < 4; ++i) {
            const size_t grow = grow0 + i;
            float v = acc[mh][nh][m][n][i];
            if (MODE == 0) {
              v += bias[gcol];
              if (gcol < 768)
                ((__hip_bfloat16*)out0)[grow * 768 + gcol] = __float2bfloat16(v);
              else
                ((__hip_bfloat16*)out1)[grow * 768 + gcol - 768] = __float2bfloat16(v);
            } else if (MODE == 1) {
              if (gcol < 768) {
                v += bias[gcol];
                float sp = (v > 20.f) ? v : log1pf(expf(v));
                ((__hip_bfloat16*)out0)[grow * 768 + gcol] = __float2bfloat16(sp);
              } else if (gcol < 784) {
                ((float*)out1)[grow * 16 + (gcol - 768)] = v;
              } else if (gcol < 800) {
                ((float*)out2)[grow * 16 + (gcol - 784)] = v;
              }
            } else {
              ((float*)out0)[grow * 768 + gcol] = v + bias[gcol];
            }
          }
        }
      }
#undef STAGE_AH
#undef STAGE_BH
#undef LOADA
#undef LOADB
#undef MMA
#undef VMW
}

// ---------------------------------------------------------------------------
// Depthwise conv1d (K=3, pad=1) + bias + SiLU.  x_in bf16 -> x_conv bf16
// ---------------------------------------------------------------------------
__global__ __launch_bounds__(256) void conv_silu(
    const __hip_bfloat16* __restrict__ xin, const float* __restrict__ conv_w,
    const float* __restrict__ conv_b, __hip_bfloat16* __restrict__ xc) {
  const int idx = blockIdx.x * 256 + threadIdx.x;  // over B*L*D
  const int d = idx % 768;
  const int t = (idx / 768) % SEQL;
  const float w0 = conv_w[d * 3], w1 = conv_w[d * 3 + 1], w2 = conv_w[d * 3 + 2];
  float acc = conv_b[d];
  float xm = (t > 0)        ? __bfloat162float(xin[idx - 768]) : 0.f;
  float x0 = __bfloat162float(xin[idx]);
  float xp = (t < SEQL - 1) ? __bfloat162float(xin[idx + 768]) : 0.f;
  acc += w0 * xm + w1 * x0 + w2 * xp;
  const float sig = 1.f / (1.f + __expf(-acc));
  xc[idx] = __float2bfloat16(acc * sig);
}

// ---------------------------------------------------------------------------
// Scan pass 1: per (b, d, chunk) local scan with h_in = 0
// ---------------------------------------------------------------------------
__global__ __launch_bounds__(256) void scan_pass1(
    const __hip_bfloat16* __restrict__ delta, const __hip_bfloat16* __restrict__ xconv,
    const float* __restrict__ Bsel, const float* __restrict__ A2,
    float* __restrict__ sumdt, float* __restrict__ Sbuf) {
  const int d = blockIdx.x * 256 + threadIdx.x;
  const int b = blockIdx.y, c = blockIdx.z;
  __shared__ float sB[TCHUNK * 16];
  ((float4*)sB)[threadIdx.x] =
      ((const float4*)(Bsel + ((size_t)b * SEQL + c * TCHUNK) * 16))[threadIdx.x];
  __syncthreads();

  float a2[16];
#pragma unroll
  for (int n = 0; n < 16; ++n) a2[n] = A2[d * 16 + n];
  float h[16] = {};
  float sdt = 0.f;
  const size_t base = ((size_t)b * SEQL + c * TCHUNK) * 768 + d;
  for (int t = 0; t < TCHUNK; ++t) {
    const float dt = __bfloat162float(delta[base + (size_t)t * 768]);
    const float x = __bfloat162float(xconv[base + (size_t)t * 768]);
    sdt += dt;
    const float dtx = dt * x;
    const float* Br = &sB[t * 16];
#pragma unroll
    for (int n = 0; n < 16; ++n) {
      const float a = exp2f(dt * a2[n]);
      h[n] = fmaf(a, h[n], dtx * Br[n]);
    }
  }
  sumdt[((size_t)b * NCHUNK + c) * 768 + d] = sdt;
#pragma unroll
  for (int n = 0; n < 16; ++n)
    Sbuf[(((size_t)b * NCHUNK + c) * 16 + n) * 768 + d] = h[n];
}

// ---------------------------------------------------------------------------
// Scan pass 2: serial carry over chunks, one thread per (b, n, d) chain.
// ---------------------------------------------------------------------------
__global__ __launch_bounds__(256) void scan_carry(
    const float* __restrict__ sumdt, const float* __restrict__ Sbuf,
    const float* __restrict__ A2, float* __restrict__ Hin) {
  const int idx = blockIdx.x * 256 + threadIdx.x;  // 0..98303
  const int d = idx % 768;
  const int n = (idx / 768) & 15;
  const int b = idx / (768 * 16);
  const float a2 = A2[d * 16 + n];
  float h = 0.f;
  for (int c = 0; c < NCHUNK; ++c) {
    const size_t hb = (((size_t)(b * NCHUNK + c)) * 16 + n) * 768 + d;
    Hin[hb] = h;
    const float sd = sumdt[(b * NCHUNK + c) * 768 + d];
    h = fmaf(exp2f(sd * a2), h, Sbuf[hb]);
  }
}

// ---------------------------------------------------------------------------
// Scan pass 3: replay with correct h_in; fuse D-skip + silu(z) gating -> bf16
// ---------------------------------------------------------------------------
__global__ __launch_bounds__(256) void scan_pass3(
    const __hip_bfloat16* __restrict__ delta, const __hip_bfloat16* __restrict__ xconv,
    const __hip_bfloat16* __restrict__ zb, const float* __restrict__ Bsel,
    const float* __restrict__ Csel, const float* __restrict__ A2,
    const float* __restrict__ Hin, const float* __restrict__ Dp,
    __hip_bfloat16* __restrict__ yg) {
  const int d = blockIdx.x * 256 + threadIdx.x;
  const int b = blockIdx.y, c = blockIdx.z;
  __shared__ float sB[TCHUNK * 16], sC[TCHUNK * 16];
  {
    const size_t off = ((size_t)b * SEQL + c * TCHUNK) * 16;
    ((float4*)sB)[threadIdx.x] = ((const float4*)(Bsel + off))[threadIdx.x];
    ((float4*)sC)[threadIdx.x] = ((const float4*)(Csel + off))[threadIdx.x];
  }
  __syncthreads();

  float a2[16];
#pragma unroll
  for (int n = 0; n < 16; ++n) a2[n] = A2[d * 16 + n];
  float h[16];
  {
    const size_t hb = ((size_t)b * NCHUNK + c) * 16 * 768 + d;
#pragma unroll
    for (int n = 0; n < 16; ++n) h[n] = Hin[hb + (size_t)n * 768];
  }
  const float Dpd = Dp[d];
  const size_t base = ((size_t)b * SEQL + c * TCHUNK) * 768 + d;
  for (int t = 0; t < TCHUNK; ++t) {
    const float dt = __bfloat162float(delta[base + (size_t)t * 768]);
    const float x = __bfloat162float(xconv[base + (size_t)t * 768]);
    const float dtx = dt * x;
    const float* Br = &sB[t * 16];
    const float* Cr = &sC[t * 16];
    float y = 0.f;
#pragma unroll
    for (int n = 0; n < 16; ++n) {
      const float a = exp2f(dt * a2[n]);
      h[n] = fmaf(a, h[n], dtx * Br[n]);
      y = fmaf(h[n], Cr[n], y);
    }
    const float z = __bfloat162float(zb[base + (size_t)t * 768]);
    const float sig = 1.f / (1.f + __expf(-z));
    const float out = (y + x * Dpd) * (z * sig);
    yg[base + (size_t)t * 768] = __float2bfloat16(out);
  }
}

// ---------------------------------------------------------------------------
// Launch
// ---------------------------------------------------------------------------
extern "C" void kernel_launch(void* const* d_in, const int* in_sizes, int n_in,
                              void* d_out, int out_size, void* d_ws, size_t ws_size,
                              hipStream_t stream) {
  const float* x       = (const float*)d_in[0];
  const float* A_log   = (const float*)d_in[1];
  const float* D_param = (const float*)d_in[2];
  const float* B_proj  = (const float*)d_in[3];
  const float* C_proj  = (const float*)d_in[4];
  const float* delta_w = (const float*)d_in[5];
  const float* delta_b = (const float*)d_in[6];
  const float* in_w    = (const float*)d_in[7];
  const float* in_b    = (const float*)d_in[8];
  const float* out_w   = (const float*)d_in[9];
  const float* out_b   = (const float*)d_in[10];
  const float* conv_w  = (const float*)d_in[11];
  const float* conv_b  = (const float*)d_in[12];

  char* ws = (char*)d_ws;
  __hip_bfloat16* xb       = (__hip_bfloat16*)(ws + 0);          // reused as yg later
  __hip_bfloat16* w_in_b   = (__hip_bfloat16*)(ws + 25165824);
  __hip_bfloat16* w_dbc_b  = (__hip_bfloat16*)(ws + 27525120);   // 1024 x 768
  __hip_bfloat16* w_out_b  = (__hip_bfloat16*)(ws + 29097984);
  float*          A2       = (float*)(ws + 30277632);
  __hip_bfloat16* xin_b    = (__hip_bfloat16*)(ws + 30326784);
  __hip_bfloat16* z_b      = (__hip_bfloat16*)(ws + 55492608);
  __hip_bfloat16* xconv_b  = (__hip_bfloat16*)(ws + 80658432);
  __hip_bfloat16* delta_bf = (__hip_bfloat16*)(ws + 105824256);
  float*          Bsel     = (float*)(ws + 130990080);
  float*          Csel     = (float*)(ws + 132038656);
  float*          sumdt    = (float*)(ws + 133087232);
  float*          Sbuf     = (float*)(ws + 133873664);
  float*          Hin      = (float*)(ws + 146456576);
  __hip_bfloat16* yg       = xb;  // x (bf16) dead after in_proj GEMM

  const int BLD = BATCH * SEQL * D_MODEL;  // 12,582,912

  // 1. prep: x->bf16, weights->bf16, A2
  prep_all<<<22320, 256, 0, stream>>>(x, in_w, delta_w, B_proj, C_proj, out_w, A_log,
                                      xb, w_in_b, w_dbc_b, w_out_b, A2);
  // 2. in_proj GEMM [16384,1536] : 64 x 6 tiles
  gemm256<0><<<384, 512, 0, stream>>>(xb, w_in_b, in_b, xin_b, z_b, nullptr, 6);
  // 3. depthwise conv + silu
  conv_silu<<<BLD / 256, 256, 0, stream>>>(xin_b, conv_w, conv_b, xconv_b);
  // 4. delta/B/C GEMM [16384,1024] : 64 x 4 tiles
  gemm256<1><<<256, 512, 0, stream>>>(xconv_b, w_dbc_b, delta_b, delta_bf, Bsel, Csel, 4);
  // 5-7. chunked scan
  scan_pass1<<<dim3(3, BATCH, NCHUNK), 256, 0, stream>>>(delta_bf, xconv_b, Bsel, A2, sumdt, Sbuf);
  scan_carry<<<384, 256, 0, stream>>>(sumdt, Sbuf, A2, Hin);
  scan_pass3<<<dim3(3, BATCH, NCHUNK), 256, 0, stream>>>(delta_bf, xconv_b, z_b, Bsel, Csel, A2,
                                                         Hin, D_param, yg);
  // 8. out_proj GEMM [16384,768] -> d_out : 64 x 3 tiles
  gemm256<2><<<192, 512, 0, stream>>>(yg, w_out_b, out_b, (float*)d_out, nullptr, nullptr, 3);
}

// Round 5
// 351.326 us; speedup vs baseline: 1.2126x; 1.0354x over previous
//
#include <hip/hip_runtime.h>
#include <hip/hip_bf16.h>

// Problem constants
#define D_MODEL 768
#define SEQL    2048
#define BATCH   8
#define NSTATE  16
#define NCHUNK  32
#define TCHUNK  64   // SEQL / NCHUNK

typedef __attribute__((ext_vector_type(8))) short short8;
typedef __attribute__((ext_vector_type(4))) float f32x4;

typedef const __attribute__((address_space(1))) unsigned int gas1_t;
typedef __attribute__((address_space(3))) unsigned int las3_t;

__device__ __forceinline__ void gload_lds16(const void* g, void* l) {
  __builtin_amdgcn_global_load_lds((gas1_t*)g, (las3_t*)l, 16, 0, 0);
}

__device__ __forceinline__ float b2f(short s) {
  return __uint_as_float(((unsigned)(unsigned short)s) << 16);
}
__device__ __forceinline__ short f2b(float f) {
  __hip_bfloat16 h = __float2bfloat16(f);
  return *reinterpret_cast<short*>(&h);
}

// ---------------------------------------------------------------------------
// Merged prep: x -> bf16 (x4/thread), weights -> bf16 (dbc padded to 1024
// rows), A2 table.  threads = 3145728 + 1179648 + 786432 + 589824 + 12288
//                           = 5713920 = 22320 * 256
// ---------------------------------------------------------------------------
__global__ __launch_bounds__(256) void prep_all(
    const float* __restrict__ x, const float* __restrict__ in_w,
    const float* __restrict__ delta_w, const float* __restrict__ Bp,
    const float* __restrict__ Cp, const float* __restrict__ out_w,
    const float* __restrict__ A_log,
    __hip_bfloat16* __restrict__ xb, __hip_bfloat16* __restrict__ w_in,
    __hip_bfloat16* __restrict__ w_dbc, __hip_bfloat16* __restrict__ w_out,
    float* __restrict__ A2) {
  int i = blockIdx.x * 256 + threadIdx.x;
  if (i < 3145728) {
    int j = i * 4;
    float4 v = *(const float4*)(x + j);
    xb[j + 0] = __float2bfloat16(v.x);
    xb[j + 1] = __float2bfloat16(v.y);
    xb[j + 2] = __float2bfloat16(v.z);
    xb[j + 3] = __float2bfloat16(v.w);
    return;
  }
  i -= 3145728;
  if (i < 1536 * 768) { w_in[i] = __float2bfloat16(in_w[i]); return; }
  i -= 1536 * 768;
  if (i < 1024 * 768) {   // 1024 rows = 768 delta + 16 B + 16 C + 224 pad
    int row = i / 768, col = i - row * 768;
    float v;
    if (row < 768)      v = delta_w[row * 768 + col];
    else if (row < 784) v = Bp[(row - 768) * 768 + col];
    else if (row < 800) v = Cp[(row - 784) * 768 + col];
    else                v = 0.f;
    w_dbc[i] = __float2bfloat16(v);
    return;
  }
  i -= 1024 * 768;
  if (i < 768 * 768) { w_out[i] = __float2bfloat16(out_w[i]); return; }
  i -= 768 * 768;
  A2[i] = -expf(A_log[i]) * 1.44269504088896f;  // A * log2(e)
}

// ---------------------------------------------------------------------------
// 256x256-tile bf16 MFMA GEMM, C[M,N] = A[M,K] * B[N,K]^T, K=768 (NT=12).
// m201-template 8-phase schedule: per K-tile 4 phases, each phase =
//   {ds_read this phase's fragments | stage one half-tile of kt+1}
//   -> barrier -> lgkmcnt(0) -> setprio(1) -> 16 MFMA -> setprio(0)
//   -> [counted vmcnt(4)] -> barrier
// Reads per tile: P0 {A0,B0}=12, P1 {B1}=4, P2 {A1}=8, P3 none (b0 held).
// Staging per tile (for kt+1): P0:A0' P1:B0' P2:B1' P3:A1'.
// vmcnt(4) at close of P0/P1/P3; never drains to 0 until peeled last tile.
// LDS 128KB: 2 dbuf x {A,B} x 2 halves x 16KB, XOR-swizzled
// (byte ^= (row&7)<<4) via pre-swizzled global source + swizzled ds_reads
// (verified 0 bank conflicts R3/R4).
// MODE 0: in_proj -> bf16 x_in (col<768) / bf16 z (col>=768), +bias
// MODE 1: dbc     -> bf16 softplus(delta+bias) (col<768), f32 B (768..783),
//                    f32 C (784..799), skip >=800
// MODE 2: out_proj-> f32 out + bias
// ---------------------------------------------------------------------------
template <int MODE>
__global__ __launch_bounds__(512, 1) void gemm256(
    const __hip_bfloat16* __restrict__ Amat, const __hip_bfloat16* __restrict__ Bw,
    const float* __restrict__ bias, void* __restrict__ out0,
    void* __restrict__ out1, void* __restrict__ out2, const int gxn) {
  constexpr int K = 768;
  constexpr int NT = K / 64;  // 12
  __shared__ char lds[131072];
  const int tid  = threadIdx.x;
  const int lane = tid & 63, wave = tid >> 6;
  const int wr = wave >> 2, wc = wave & 3;   // 2M x 4N

  // bijective XCD swizzle; also confines each A-panel (tm) to one XCD's L2.
  const int nwg = gridDim.x, id = blockIdx.x;
  const int swz = (id & 7) * (nwg >> 3) + (id >> 3);
  const int tm = swz / gxn, tn = swz - tm * gxn;
  const int rowA0 = tm * 256, rowB0 = tn * 256;

  // staging source (inverse-swizzled global source, linear LDS dest)
  const int srow0 = tid >> 3;                                  // 0..63
  const int scol  = (((tid & 7) ^ (srow0 & 7)) << 3);          // elem col
  const __hip_bfloat16* gA = Amat + (size_t)(rowA0 + srow0) * K + scol;
  const __hip_bfloat16* gB = Bw   + (size_t)(rowB0 + srow0) * K + scol;
  const int ldst = tid << 4;

  // fragment reads (swizzled ds_read address)
  const int frow = lane & 15, fq = lane >> 4;
  const int fswz = (frow & 7) << 4;
  const int pc0 = (fq << 4) ^ fswz;
  const int pc1 = (64 | (fq << 4)) ^ fswz;
  const int aro = (wr * 64 + frow) << 7;   // byte row offset within A-half
  const int bro = (wc * 32 + frow) << 7;   // byte row offset within B-half

  f32x4 acc[2][2][4][2];
#pragma unroll
  for (int mh = 0; mh < 2; ++mh)
#pragma unroll
    for (int nh = 0; nh < 2; ++nh)
#pragma unroll
      for (int m = 0; m < 4; ++m)
#pragma unroll
        for (int n = 0; n < 2; ++n) acc[mh][nh][m][n] = (f32x4){0.f, 0.f, 0.f, 0.f};

  // LDS bases: A[d][h] = d*65536 + h*16384 ; B[d][h] = d*65536 + 32768 + h*16384
#define STAGE_AH(d, h, kt)                                                      \
  {                                                                             \
    const __hip_bfloat16* s0 = gA + (size_t)((h)*128) * K + (kt)*64;            \
    char* d0 = lds + ((d) << 16) + ((h) << 14) + ldst;                          \
    gload_lds16(s0, d0);                                                        \
    gload_lds16(s0 + (size_t)64 * K, d0 + 8192);                                \
  }
#define STAGE_BH(d, h, kt)                                                      \
  {                                                                             \
    const __hip_bfloat16* s0 = gB + (size_t)((h)*128) * K + (kt)*64;            \
    char* d0 = lds + ((d) << 16) + 32768 + ((h) << 14) + ldst;                  \
    gload_lds16(s0, d0);                                                        \
    gload_lds16(s0 + (size_t)64 * K, d0 + 8192);                                \
  }

  short8 aE[4][2], aO[4][2], b0[2][2], b1[2][2];
#define RD_A(dst, d, h)                                                         \
  {                                                                             \
    const char* base = lds + ((d) << 16) + ((h) << 14) + aro;                   \
    _Pragma("unroll") for (int m = 0; m < 4; ++m) {                             \
      const char* p = base + ((m * 16) << 7);                                   \
      dst[m][0] = *(const short8*)(p + pc0);                                    \
      dst[m][1] = *(const short8*)(p + pc1);                                    \
    }                                                                           \
  }
#define RD_B(dst, d, h)                                                         \
  {                                                                             \
    const char* base = lds + ((d) << 16) + 32768 + ((h) << 14) + bro;           \
    _Pragma("unroll") for (int n = 0; n < 2; ++n) {                             \
      const char* p = base + ((n * 16) << 7);                                   \
      dst[n][0] = *(const short8*)(p + pc0);                                    \
      dst[n][1] = *(const short8*)(p + pc1);                                    \
    }                                                                           \
  }
#define MMA(mh, nh, A, B)                                                       \
  {                                                                             \
    __builtin_amdgcn_s_setprio(1);                                              \
    _Pragma("unroll") for (int m = 0; m < 4; ++m)                               \
    _Pragma("unroll") for (int n = 0; n < 2; ++n)                               \
    _Pragma("unroll") for (int ks = 0; ks < 2; ++ks)                            \
        acc[mh][nh][m][n] = __builtin_amdgcn_mfma_f32_16x16x32_bf16(            \
            A[m][ks], B[n][ks], acc[mh][nh][m][n], 0, 0, 0);                    \
    __builtin_amdgcn_s_setprio(0);                                              \
  }
#define VMW(n) asm volatile("s_waitcnt vmcnt(" #n ")" ::: "memory")
#define LGKM0  asm volatile("s_waitcnt lgkmcnt(0)" ::: "memory")
#define BAR    __builtin_amdgcn_s_barrier()

  // prologue: stage tile 0 (A0,B0,B1,A1); wait A0,B0; barrier.
  STAGE_AH(0, 0, 0);
  STAGE_BH(0, 0, 0);
  STAGE_BH(0, 1, 0);
  STAGE_AH(0, 1, 0);
  VMW(4);
  BAR;

  for (int kt = 0; kt < NT - 1; ++kt) {
    const int cur = kt & 1, nxt = cur ^ 1;
    // P0: reads A0,B0(cur); stage A0(kt+1)
    RD_A(aE, cur, 0);
    RD_B(b0, cur, 0);
    STAGE_AH(nxt, 0, kt + 1);
    BAR; LGKM0;
    MMA(0, 0, aE, b0);
    VMW(4);   // retire B1(cur)
    BAR;
    // P1: reads B1(cur); stage B0(kt+1)
    RD_B(b1, cur, 1);
    STAGE_BH(nxt, 0, kt + 1);
    BAR; LGKM0;
    MMA(0, 1, aE, b1);
    VMW(4);   // retire A1(cur)
    BAR;
    // P2: reads A1(cur); stage B1(kt+1)
    RD_A(aO, cur, 1);
    STAGE_BH(nxt, 1, kt + 1);
    BAR; LGKM0;
    MMA(1, 1, aO, b1);
    BAR;
    // P3: no reads (b0 held); stage A1(kt+1)
    STAGE_AH(nxt, 1, kt + 1);
    BAR;
    MMA(1, 0, aO, b0);
    VMW(4);   // retire A0,B0(kt+1)
    BAR;
  }
  {  // peeled last K-tile (NT-1 = 11, cur = 1); tighten vmcnt 2/0
    const int cur = (NT - 1) & 1;
    RD_A(aE, cur, 0);
    RD_B(b0, cur, 0);
    BAR; LGKM0;
    MMA(0, 0, aE, b0);
    VMW(2);
    BAR;
    RD_B(b1, cur, 1);
    BAR; LGKM0;
    MMA(0, 1, aE, b1);
    VMW(0);
    BAR;
    RD_A(aO, cur, 1);
    BAR; LGKM0;
    MMA(1, 1, aO, b1);
    BAR;
    MMA(1, 0, aO, b0);
  }

  // epilogue (C/D layout: col = lane&15, row = (lane>>4)*4 + i)
#pragma unroll
  for (int mh = 0; mh < 2; ++mh)
#pragma unroll
    for (int nh = 0; nh < 2; ++nh)
#pragma unroll
      for (int m = 0; m < 4; ++m) {
        const int grow0 = rowA0 + mh * 128 + wr * 64 + m * 16 + fq * 4;
#pragma unroll
        for (int n = 0; n < 2; ++n) {
          const int gcol = rowB0 + nh * 128 + wc * 32 + n * 16 + frow;
#pragma unroll
          for (int i = 0; i < 4; ++i) {
            const size_t grow = grow0 + i;
            float v = acc[mh][nh][m][n][i];
            if (MODE == 0) {
              v += bias[gcol];
              if (gcol < 768)
                ((__hip_bfloat16*)out0)[grow * 768 + gcol] = __float2bfloat16(v);
              else
                ((__hip_bfloat16*)out1)[grow * 768 + gcol - 768] = __float2bfloat16(v);
            } else if (MODE == 1) {
              if (gcol < 768) {
                v += bias[gcol];
                float sp = (v > 20.f) ? v : log1pf(expf(v));
                ((__hip_bfloat16*)out0)[grow * 768 + gcol] = __float2bfloat16(sp);
              } else if (gcol < 784) {
                ((float*)out1)[grow * 16 + (gcol - 768)] = v;
              } else if (gcol < 800) {
                ((float*)out2)[grow * 16 + (gcol - 784)] = v;
              }
            } else {
              ((float*)out0)[grow * 768 + gcol] = v + bias[gcol];
            }
          }
        }
      }
#undef STAGE_AH
#undef STAGE_BH
#undef RD_A
#undef RD_B
#undef MMA
#undef VMW
#undef LGKM0
#undef BAR
}

// ---------------------------------------------------------------------------
// Depthwise conv1d (K=3, pad=1) + bias + SiLU, short8-vectorized.
// Thread handles 8 consecutive d.  grid = BLD/8/256 = 6144 blocks.
// ---------------------------------------------------------------------------
__global__ __launch_bounds__(256) void conv_silu8(
    const __hip_bfloat16* __restrict__ xin, const float* __restrict__ conv_w,
    const float* __restrict__ conv_b, __hip_bfloat16* __restrict__ xc) {
  const int idx = blockIdx.x * 256 + threadIdx.x;   // over BLD/8
  const int d8 = (idx % 96) * 8;
  const int t  = (idx / 96) % SEQL;
  const size_t base = (size_t)idx * 8;

  short8 x0 = *(const short8*)(xin + base);
  short8 xm = {}, xp = {};
  if (t > 0)        xm = *(const short8*)(xin + base - 768);
  if (t < SEQL - 1) xp = *(const short8*)(xin + base + 768);

  const float4* cw4 = (const float4*)(conv_w + d8 * 3);  // 24 floats
  float4 cw[6];
#pragma unroll
  for (int q = 0; q < 6; ++q) cw[q] = cw4[q];
  float4 cb0 = *(const float4*)(conv_b + d8);
  float4 cb1 = *(const float4*)(conv_b + d8 + 4);
  const float* cwf = (const float*)cw;
  const float* cbf0 = (const float*)&cb0;
  const float* cbf1 = (const float*)&cb1;

  short8 r;
#pragma unroll
  for (int e = 0; e < 8; ++e) {
    float acc = (e < 4) ? cbf0[e] : cbf1[e - 4];
    acc = fmaf(cwf[e * 3 + 0], b2f(xm[e]), acc);
    acc = fmaf(cwf[e * 3 + 1], b2f(x0[e]), acc);
    acc = fmaf(cwf[e * 3 + 2], b2f(xp[e]), acc);
    const float sig = 1.f / (1.f + __expf(-acc));
    r[e] = f2b(acc * sig);
  }
  *(short8*)(xc + base) = r;
}

// ---------------------------------------------------------------------------
// Scan pass 1: per (b, d, chunk) local scan with h_in = 0
// ---------------------------------------------------------------------------
__global__ __launch_bounds__(256) void scan_pass1(
    const __hip_bfloat16* __restrict__ delta, const __hip_bfloat16* __restrict__ xconv,
    const float* __restrict__ Bsel, const float* __restrict__ A2,
    float* __restrict__ sumdt, float* __restrict__ Sbuf) {
  const int d = blockIdx.x * 256 + threadIdx.x;
  const int b = blockIdx.y, c = blockIdx.z;
  __shared__ float sB[TCHUNK * 16];
  ((float4*)sB)[threadIdx.x] =
      ((const float4*)(Bsel + ((size_t)b * SEQL + c * TCHUNK) * 16))[threadIdx.x];
  __syncthreads();

  float a2[16];
#pragma unroll
  for (int n = 0; n < 16; ++n) a2[n] = A2[d * 16 + n];
  float h[16] = {};
  float sdt = 0.f;
  const size_t base = ((size_t)b * SEQL + c * TCHUNK) * 768 + d;
  for (int t = 0; t < TCHUNK; ++t) {
    const float dt = b2f(((const short*)delta)[base + (size_t)t * 768]);
    const float x = b2f(((const short*)xconv)[base + (size_t)t * 768]);
    sdt += dt;
    const float dtx = dt * x;
    const float* Br = &sB[t * 16];
#pragma unroll
    for (int n = 0; n < 16; ++n) {
      const float a = exp2f(dt * a2[n]);
      h[n] = fmaf(a, h[n], dtx * Br[n]);
    }
  }
  sumdt[((size_t)b * NCHUNK + c) * 768 + d] = sdt;
#pragma unroll
  for (int n = 0; n < 16; ++n)
    Sbuf[(((size_t)b * NCHUNK + c) * 16 + n) * 768 + d] = h[n];
}

// ---------------------------------------------------------------------------
// Scan pass 2: serial carry over chunks, one thread per (b, n, d) chain.
// ---------------------------------------------------------------------------
__global__ __launch_bounds__(256) void scan_carry(
    const float* __restrict__ sumdt, const float* __restrict__ Sbuf,
    const float* __restrict__ A2, float* __restrict__ Hin) {
  const int idx = blockIdx.x * 256 + threadIdx.x;  // 0..98303
  const int d = idx % 768;
  const int n = (idx / 768) & 15;
  const int b = idx / (768 * 16);
  const float a2 = A2[d * 16 + n];
  float h = 0.f;
  for (int c = 0; c < NCHUNK; ++c) {
    const size_t hb = (((size_t)(b * NCHUNK + c)) * 16 + n) * 768 + d;
    Hin[hb] = h;
    const float sd = sumdt[(b * NCHUNK + c) * 768 + d];
    h = fmaf(exp2f(sd * a2), h, Sbuf[hb]);
  }
}

// ---------------------------------------------------------------------------
// Scan pass 3: replay with correct h_in; fuse D-skip + silu(z) gating -> bf16
// ---------------------------------------------------------------------------
__global__ __launch_bounds__(256) void scan_pass3(
    const __hip_bfloat16* __restrict__ delta, const __hip_bfloat16* __restrict__ xconv,
    const __hip_bfloat16* __restrict__ zb, const float* __restrict__ Bsel,
    const float* __restrict__ Csel, const float* __restrict__ A2,
    const float* __restrict__ Hin, const float* __restrict__ Dp,
    __hip_bfloat16* __restrict__ yg) {
  const int d = blockIdx.x * 256 + threadIdx.x;
  const int b = blockIdx.y, c = blockIdx.z;
  __shared__ float sB[TCHUNK * 16], sC[TCHUNK * 16];
  {
    const size_t off = ((size_t)b * SEQL + c * TCHUNK) * 16;
    ((float4*)sB)[threadIdx.x] = ((const float4*)(Bsel + off))[threadIdx.x];
    ((float4*)sC)[threadIdx.x] = ((const float4*)(Csel + off))[threadIdx.x];
  }
  __syncthreads();

  float a2[16];
#pragma unroll
  for (int n = 0; n < 16; ++n) a2[n] = A2[d * 16 + n];
  float h[16];
  {
    const size_t hb = ((size_t)b * NCHUNK + c) * 16 * 768 + d;
#pragma unroll
    for (int n = 0; n < 16; ++n) h[n] = Hin[hb + (size_t)n * 768];
  }
  const float Dpd = Dp[d];
  const size_t base = ((size_t)b * SEQL + c * TCHUNK) * 768 + d;
  for (int t = 0; t < TCHUNK; ++t) {
    const float dt = b2f(((const short*)delta)[base + (size_t)t * 768]);
    const float x = b2f(((const short*)xconv)[base + (size_t)t * 768]);
    const float dtx = dt * x;
    const float* Br = &sB[t * 16];
    const float* Cr = &sC[t * 16];
    float y = 0.f;
#pragma unroll
    for (int n = 0; n < 16; ++n) {
      const float a = exp2f(dt * a2[n]);
      h[n] = fmaf(a, h[n], dtx * Br[n]);
      y = fmaf(h[n], Cr[n], y);
    }
    const float z = b2f(((const short*)zb)[base + (size_t)t * 768]);
    const float sig = 1.f / (1.f + __expf(-z));
    const float out = (y + x * Dpd) * (z * sig);
    yg[base + (size_t)t * 768] = __float2bfloat16(out);
  }
}

// ---------------------------------------------------------------------------
// Launch
// ---------------------------------------------------------------------------
extern "C" void kernel_launch(void* const* d_in, const int* in_sizes, int n_in,
                              void* d_out, int out_size, void* d_ws, size_t ws_size,
                              hipStream_t stream) {
  const float* x       = (const float*)d_in[0];
  const float* A_log   = (const float*)d_in[1];
  const float* D_param = (const float*)d_in[2];
  const float* B_proj  = (const float*)d_in[3];
  const float* C_proj  = (const float*)d_in[4];
  const float* delta_w = (const float*)d_in[5];
  const float* delta_b = (const float*)d_in[6];
  const float* in_w    = (const float*)d_in[7];
  const float* in_b    = (const float*)d_in[8];
  const float* out_w   = (const float*)d_in[9];
  const float* out_b   = (const float*)d_in[10];
  const float* conv_w  = (const float*)d_in[11];
  const float* conv_b  = (const float*)d_in[12];

  char* ws = (char*)d_ws;
  __hip_bfloat16* xb       = (__hip_bfloat16*)(ws + 0);          // reused as yg later
  __hip_bfloat16* w_in_b   = (__hip_bfloat16*)(ws + 25165824);
  __hip_bfloat16* w_dbc_b  = (__hip_bfloat16*)(ws + 27525120);   // 1024 x 768
  __hip_bfloat16* w_out_b  = (__hip_bfloat16*)(ws + 29097984);
  float*          A2       = (float*)(ws + 30277632);
  __hip_bfloat16* xin_b    = (__hip_bfloat16*)(ws + 30326784);
  __hip_bfloat16* z_b      = (__hip_bfloat16*)(ws + 55492608);
  __hip_bfloat16* xconv_b  = (__hip_bfloat16*)(ws + 80658432);
  __hip_bfloat16* delta_bf = (__hip_bfloat16*)(ws + 105824256);
  float*          Bsel     = (float*)(ws + 130990080);
  float*          Csel     = (float*)(ws + 132038656);
  float*          sumdt    = (float*)(ws + 133087232);
  float*          Sbuf     = (float*)(ws + 133873664);
  float*          Hin      = (float*)(ws + 146456576);
  __hip_bfloat16* yg       = xb;  // x (bf16) dead after in_proj GEMM

  const int BLD = BATCH * SEQL * D_MODEL;  // 12,582,912

  // 1. prep: x->bf16, weights->bf16, A2
  prep_all<<<22320, 256, 0, stream>>>(x, in_w, delta_w, B_proj, C_proj, out_w, A_log,
                                      xb, w_in_b, w_dbc_b, w_out_b, A2);
  // 2. in_proj GEMM [16384,1536] : 64 x 6 tiles
  gemm256<0><<<384, 512, 0, stream>>>(xb, w_in_b, in_b, xin_b, z_b, nullptr, 6);
  // 3. depthwise conv + silu (short8)
  conv_silu8<<<BLD / 8 / 256, 256, 0, stream>>>(xin_b, conv_w, conv_b, xconv_b);
  // 4. delta/B/C GEMM [16384,1024] : 64 x 4 tiles
  gemm256<1><<<256, 512, 0, stream>>>(xconv_b, w_dbc_b, delta_b, delta_bf, Bsel, Csel, 4);
  // 5-7. chunked scan
  scan_pass1<<<dim3(3, BATCH, NCHUNK), 256, 0, stream>>>(delta_bf, xconv_b, Bsel, A2, sumdt, Sbuf);
  scan_carry<<<384, 256, 0, stream>>>(sumdt, Sbuf, A2, Hin);
  scan_pass3<<<dim3(3, BATCH, NCHUNK), 256, 0, stream>>>(delta_bf, xconv_b, z_b, Bsel, Csel, A2,
                                                         Hin, D_param, yg);
  // 8. out_proj GEMM [16384,768] -> d_out : 64 x 3 tiles
  gemm256<2><<<192, 512, 0, stream>>>(yg, w_out_b, out_b, (float*)d_out, nullptr, nullptr, 3);
}

// Round 6
// 347.031 us; speedup vs baseline: 1.2276x; 1.0124x over previous
//
#include <hip/hip_runtime.h>
#include <hip/hip_bf16.h>

// Problem constants
#define D_MODEL 768
#define SEQL    2048
#define BATCH   8
#define NSTATE  16
#define NCHUNK  32
#define TCHUNK  64   // SEQL / NCHUNK

typedef __attribute__((ext_vector_type(8))) short short8;
typedef __attribute__((ext_vector_type(4))) float f32x4;

typedef const __attribute__((address_space(1))) unsigned int gas1_t;
typedef __attribute__((address_space(3))) unsigned int las3_t;

__device__ __forceinline__ void gload_lds16(const void* g, void* l) {
  __builtin_amdgcn_global_load_lds((gas1_t*)g, (las3_t*)l, 16, 0, 0);
}

__device__ __forceinline__ float b2f(short s) {
  return __uint_as_float(((unsigned)(unsigned short)s) << 16);
}
__device__ __forceinline__ short f2b(float f) {
  __hip_bfloat16 h = __float2bfloat16(f);
  return *reinterpret_cast<short*>(&h);
}

// ---------------------------------------------------------------------------
// Merged prep: x -> bf16 (x4/thread), weights -> bf16 (dbc 896 rows), A2.
// threads = 3145728 + 1179648 + 688128 + 589824 + 12288 = 5615616 = 21936*256
// ---------------------------------------------------------------------------
__global__ __launch_bounds__(256) void prep_all(
    const float* __restrict__ x, const float* __restrict__ in_w,
    const float* __restrict__ delta_w, const float* __restrict__ Bp,
    const float* __restrict__ Cp, const float* __restrict__ out_w,
    const float* __restrict__ A_log,
    __hip_bfloat16* __restrict__ xb, __hip_bfloat16* __restrict__ w_in,
    __hip_bfloat16* __restrict__ w_dbc, __hip_bfloat16* __restrict__ w_out,
    float* __restrict__ A2) {
  int i = blockIdx.x * 256 + threadIdx.x;
  if (i < 3145728) {
    int j = i * 4;
    float4 v = *(const float4*)(x + j);
    xb[j + 0] = __float2bfloat16(v.x);
    xb[j + 1] = __float2bfloat16(v.y);
    xb[j + 2] = __float2bfloat16(v.z);
    xb[j + 3] = __float2bfloat16(v.w);
    return;
  }
  i -= 3145728;
  if (i < 1536 * 768) { w_in[i] = __float2bfloat16(in_w[i]); return; }
  i -= 1536 * 768;
  if (i < 896 * 768) {   // 896 rows = 768 delta + 16 B + 16 C + 96 pad
    int row = i / 768, col = i - row * 768;
    float v;
    if (row < 768)      v = delta_w[row * 768 + col];
    else if (row < 784) v = Bp[(row - 768) * 768 + col];
    else if (row < 800) v = Cp[(row - 784) * 768 + col];
    else                v = 0.f;
    w_dbc[i] = __float2bfloat16(v);
    return;
  }
  i -= 896 * 768;
  if (i < 768 * 768) { w_out[i] = __float2bfloat16(out_w[i]); return; }
  i -= 768 * 768;
  A2[i] = -expf(A_log[i]) * 1.44269504088896f;  // A * log2(e)
}

// ---------------------------------------------------------------------------
// 128x128-tile bf16 MFMA GEMM, C[M,N] = A[M,K] * B[N,K]^T, K=768 (24 x BK=32).
// 256 threads = 4 waves (2x2), per-wave 64x64 (acc = 64 VGPR).  TLP design:
// LDS = 3 bufs x (A 8KB + B 8KB) = 48KB -> 3 blocks/CU = 12 waves/CU, so the
// CU scheduler co-schedules 3 independent barrier groups (m114 overlap).
// Per phase (= 1 K-tile): {8 ds_read_b128 | stage tile kt+2 (4 gloads)} ->
// 16 MFMA -> vmcnt(4) -> barrier.  Issue-to-wait distance ~2 phases; vmcnt
// never drains to 0 until the tail (m218 counted-vmcnt).
// Swizzle for 64B rows: 16B-slot ^= (row>>1)&3  => 2 lanes/bank (free, m136),
// applied both-sides (inverse-swizzled global source, linear gload dest,
// swizzled ds_read).
// MODE 0: in_proj -> bf16 x_in (col<768) / bf16 z (col>=768), +bias
// MODE 1: dbc     -> bf16 softplus(delta+bias) (col<768), f32 B (768..783),
//                    f32 C (784..799), skip >=800
// MODE 2: out_proj-> f32 out + bias
// ---------------------------------------------------------------------------
template <int MODE>
__global__ __launch_bounds__(256, 3) void gemm128tb(
    const __hip_bfloat16* __restrict__ Amat, const __hip_bfloat16* __restrict__ Bw,
    const float* __restrict__ bias, void* __restrict__ out0,
    void* __restrict__ out1, void* __restrict__ out2, const int gxn) {
  constexpr int K  = 768;
  constexpr int KT = 24;           // K / 32
  __shared__ char lds[49152];      // 3 x 16KB
  const int tid  = threadIdx.x;
  const int lane = tid & 63, wave = tid >> 6;
  const int wr = wave >> 1, wc = wave & 1;

  // bijective XCD swizzle (all grids divisible by 8); consecutive swz share tm
  // (the A panel) for L2 locality.
  const int nwg = gridDim.x, id = blockIdx.x;
  const int swz = (id & 7) * (nwg >> 3) + (id >> 3);
  const int tm = swz / gxn, tn = swz - tm * gxn;
  const int rowA0 = tm * 128, rowB0 = tn * 128;

  // staging source (inverse-swizzled): thread t covers LDS bytes t*16 (row
  // t>>2, slot t&3) and +4096 (row +64, same slot).
  const int srow = tid >> 2;                                   // 0..63
  const int scol = (((tid & 3) ^ ((srow >> 1) & 3)) << 3);     // elem col
  const __hip_bfloat16* gA = Amat + (size_t)(rowA0 + srow) * K + scol;
  const __hip_bfloat16* gB = Bw   + (size_t)(rowB0 + srow) * K + scol;
  const int ldst = tid << 4;

  // fragment ds_read offsets (swizzled)
  const int frow = lane & 15, fq = lane >> 4;
  const int pc = (fq << 4) ^ (((frow >> 1) & 3) << 4);
  const int aoff = ((wr * 64 + frow) << 6) + pc;   // 64B rows
  const int boff = ((wc * 64 + frow) << 6) + pc;

  f32x4 acc[4][4];
#pragma unroll
  for (int m = 0; m < 4; ++m)
#pragma unroll
    for (int n = 0; n < 4; ++n) acc[m][n] = (f32x4){0.f, 0.f, 0.f, 0.f};

#define STAGE(buf, kt)                                                          \
  {                                                                             \
    const __hip_bfloat16* sA = gA + (kt) * 32;                                  \
    const __hip_bfloat16* sB = gB + (kt) * 32;                                  \
    char* dA = lds + (buf) * 16384 + ldst;                                      \
    char* dB = dA + 8192;                                                       \
    gload_lds16(sA, dA);                                                        \
    gload_lds16(sA + (size_t)64 * K, dA + 4096);                                \
    gload_lds16(sB, dB);                                                        \
    gload_lds16(sB + (size_t)64 * K, dB + 4096);                                \
  }
#define VMW(n) asm volatile("s_waitcnt vmcnt(" #n ")" ::: "memory")
#define BAR    __builtin_amdgcn_s_barrier()

  // prologue: stage tiles 0,1 into bufs 0,1; retire tile 0; barrier.
  STAGE(0, 0);
  STAGE(1, 1);
  VMW(4);
  BAR;

  int bc = 0;  // current buffer = kt % 3
  for (int kt = 0; kt < KT; ++kt) {
    // ds_read this tile's fragments (data retired before last barrier)
    short8 a[4], b[4];
    const char* ba = lds + bc * 16384;
#pragma unroll
    for (int m = 0; m < 4; ++m) a[m] = *(const short8*)(ba + aoff + m * 1024);
#pragma unroll
    for (int n = 0; n < 4; ++n) b[n] = *(const short8*)(ba + 8192 + boff + n * 1024);
    // stage tile kt+2 into buffer (bc+2)%3
    const bool st = (kt + 2 < KT);
    if (st) {
      const int b2 = bc + 2 >= 3 ? bc - 1 : bc + 2;
      STAGE(b2, kt + 2);
    }
    // MFMA (compiler inserts lgkmcnt for the a/b dataflow)
    __builtin_amdgcn_s_setprio(1);
#pragma unroll
    for (int m = 0; m < 4; ++m)
#pragma unroll
      for (int n = 0; n < 4; ++n)
        acc[m][n] = __builtin_amdgcn_mfma_f32_16x16x32_bf16(a[m], b[n], acc[m][n], 0, 0, 0);
    __builtin_amdgcn_s_setprio(0);
    // counted wait: retire tile kt+1's 4 loads (issued ~2 phases ago);
    // tail: kt+2==KT -> retire last tile's loads; kt==KT-1 -> nothing.
    if (st)                VMW(4);
    else if (kt + 2 == KT) VMW(0);
    BAR;
    bc = bc + 1 >= 3 ? 0 : bc + 1;
  }

  // epilogue (C/D layout: col = lane&15, row = (lane>>4)*4 + i)
#pragma unroll
  for (int m = 0; m < 4; ++m) {
    const int grow0 = rowA0 + wr * 64 + m * 16 + fq * 4;
#pragma unroll
    for (int n = 0; n < 4; ++n) {
      const int gcol = rowB0 + wc * 64 + n * 16 + frow;
#pragma unroll
      for (int i = 0; i < 4; ++i) {
        const size_t grow = grow0 + i;
        float v = acc[m][n][i];
        if (MODE == 0) {
          v += bias[gcol];
          if (gcol < 768)
            ((__hip_bfloat16*)out0)[grow * 768 + gcol] = __float2bfloat16(v);
          else
            ((__hip_bfloat16*)out1)[grow * 768 + gcol - 768] = __float2bfloat16(v);
        } else if (MODE == 1) {
          if (gcol < 768) {
            v += bias[gcol];
            float sp = (v > 20.f) ? v : log1pf(expf(v));
            ((__hip_bfloat16*)out0)[grow * 768 + gcol] = __float2bfloat16(sp);
          } else if (gcol < 784) {
            ((float*)out1)[grow * 16 + (gcol - 768)] = v;
          } else if (gcol < 800) {
            ((float*)out2)[grow * 16 + (gcol - 784)] = v;
          }
        } else {
          ((float*)out0)[grow * 768 + gcol] = v + bias[gcol];
        }
      }
    }
  }
#undef STAGE
#undef VMW
#undef BAR
}

// ---------------------------------------------------------------------------
// Depthwise conv1d (K=3, pad=1) + bias + SiLU, short8-vectorized.
// ---------------------------------------------------------------------------
__global__ __launch_bounds__(256) void conv_silu8(
    const __hip_bfloat16* __restrict__ xin, const float* __restrict__ conv_w,
    const float* __restrict__ conv_b, __hip_bfloat16* __restrict__ xc) {
  const int idx = blockIdx.x * 256 + threadIdx.x;   // over BLD/8
  const int d8 = (idx % 96) * 8;
  const int t  = (idx / 96) % SEQL;
  const size_t base = (size_t)idx * 8;

  short8 x0 = *(const short8*)(xin + base);
  short8 xm = {}, xp = {};
  if (t > 0)        xm = *(const short8*)(xin + base - 768);
  if (t < SEQL - 1) xp = *(const short8*)(xin + base + 768);

  const float4* cw4 = (const float4*)(conv_w + d8 * 3);  // 24 floats
  float4 cw[6];
#pragma unroll
  for (int q = 0; q < 6; ++q) cw[q] = cw4[q];
  float4 cb0 = *(const float4*)(conv_b + d8);
  float4 cb1 = *(const float4*)(conv_b + d8 + 4);
  const float* cwf = (const float*)cw;
  const float* cbf0 = (const float*)&cb0;
  const float* cbf1 = (const float*)&cb1;

  short8 r;
#pragma unroll
  for (int e = 0; e < 8; ++e) {
    float acc = (e < 4) ? cbf0[e] : cbf1[e - 4];
    acc = fmaf(cwf[e * 3 + 0], b2f(xm[e]), acc);
    acc = fmaf(cwf[e * 3 + 1], b2f(x0[e]), acc);
    acc = fmaf(cwf[e * 3 + 2], b2f(xp[e]), acc);
    const float sig = 1.f / (1.f + __expf(-acc));
    r[e] = f2b(acc * sig);
  }
  *(short8*)(xc + base) = r;
}

// ---------------------------------------------------------------------------
// Scan pass 1: per (b, d, chunk) local scan with h_in = 0
// ---------------------------------------------------------------------------
__global__ __launch_bounds__(256) void scan_pass1(
    const __hip_bfloat16* __restrict__ delta, const __hip_bfloat16* __restrict__ xconv,
    const float* __restrict__ Bsel, const float* __restrict__ A2,
    float* __restrict__ sumdt, float* __restrict__ Sbuf) {
  const int d = blockIdx.x * 256 + threadIdx.x;
  const int b = blockIdx.y, c = blockIdx.z;
  __shared__ float sB[TCHUNK * 16];
  ((float4*)sB)[threadIdx.x] =
      ((const float4*)(Bsel + ((size_t)b * SEQL + c * TCHUNK) * 16))[threadIdx.x];
  __syncthreads();

  float a2[16];
#pragma unroll
  for (int n = 0; n < 16; ++n) a2[n] = A2[d * 16 + n];
  float h[16] = {};
  float sdt = 0.f;
  const size_t base = ((size_t)b * SEQL + c * TCHUNK) * 768 + d;
  for (int t = 0; t < TCHUNK; ++t) {
    const float dt = b2f(((const short*)delta)[base + (size_t)t * 768]);
    const float x = b2f(((const short*)xconv)[base + (size_t)t * 768]);
    sdt += dt;
    const float dtx = dt * x;
    const float* Br = &sB[t * 16];
#pragma unroll
    for (int n = 0; n < 16; ++n) {
      const float a = exp2f(dt * a2[n]);
      h[n] = fmaf(a, h[n], dtx * Br[n]);
    }
  }
  sumdt[((size_t)b * NCHUNK + c) * 768 + d] = sdt;
#pragma unroll
  for (int n = 0; n < 16; ++n)
    Sbuf[(((size_t)b * NCHUNK + c) * 16 + n) * 768 + d] = h[n];
}

// ---------------------------------------------------------------------------
// Scan pass 2: serial carry over chunks, one thread per (b, n, d) chain.
// ---------------------------------------------------------------------------
__global__ __launch_bounds__(256) void scan_carry(
    const float* __restrict__ sumdt, const float* __restrict__ Sbuf,
    const float* __restrict__ A2, float* __restrict__ Hin) {
  const int idx = blockIdx.x * 256 + threadIdx.x;  // 0..98303
  const int d = idx % 768;
  const int n = (idx / 768) & 15;
  const int b = idx / (768 * 16);
  const float a2 = A2[d * 16 + n];
  float h = 0.f;
  for (int c = 0; c < NCHUNK; ++c) {
    const size_t hb = (((size_t)(b * NCHUNK + c)) * 16 + n) * 768 + d;
    Hin[hb] = h;
    const float sd = sumdt[(b * NCHUNK + c) * 768 + d];
    h = fmaf(exp2f(sd * a2), h, Sbuf[hb]);
  }
}

// ---------------------------------------------------------------------------
// Scan pass 3: replay with correct h_in; fuse D-skip + silu(z) gating -> bf16
// ---------------------------------------------------------------------------
__global__ __launch_bounds__(256) void scan_pass3(
    const __hip_bfloat16* __restrict__ delta, const __hip_bfloat16* __restrict__ xconv,
    const __hip_bfloat16* __restrict__ zb, const float* __restrict__ Bsel,
    const float* __restrict__ Csel, const float* __restrict__ A2,
    const float* __restrict__ Hin, const float* __restrict__ Dp,
    __hip_bfloat16* __restrict__ yg) {
  const int d = blockIdx.x * 256 + threadIdx.x;
  const int b = blockIdx.y, c = blockIdx.z;
  __shared__ float sB[TCHUNK * 16], sC[TCHUNK * 16];
  {
    const size_t off = ((size_t)b * SEQL + c * TCHUNK) * 16;
    ((float4*)sB)[threadIdx.x] = ((const float4*)(Bsel + off))[threadIdx.x];
    ((float4*)sC)[threadIdx.x] = ((const float4*)(Csel + off))[threadIdx.x];
  }
  __syncthreads();

  float a2[16];
#pragma unroll
  for (int n = 0; n < 16; ++n) a2[n] = A2[d * 16 + n];
  float h[16];
  {
    const size_t hb = ((size_t)b * NCHUNK + c) * 16 * 768 + d;
#pragma unroll
    for (int n = 0; n < 16; ++n) h[n] = Hin[hb + (size_t)n * 768];
  }
  const float Dpd = Dp[d];
  const size_t base = ((size_t)b * SEQL + c * TCHUNK) * 768 + d;
  for (int t = 0; t < TCHUNK; ++t) {
    const float dt = b2f(((const short*)delta)[base + (size_t)t * 768]);
    const float x = b2f(((const short*)xconv)[base + (size_t)t * 768]);
    const float dtx = dt * x;
    const float* Br = &sB[t * 16];
    const float* Cr = &sC[t * 16];
    float y = 0.f;
#pragma unroll
    for (int n = 0; n < 16; ++n) {
      const float a = exp2f(dt * a2[n]);
      h[n] = fmaf(a, h[n], dtx * Br[n]);
      y = fmaf(h[n], Cr[n], y);
    }
    const float z = b2f(((const short*)zb)[base + (size_t)t * 768]);
    const float sig = 1.f / (1.f + __expf(-z));
    const float out = (y + x * Dpd) * (z * sig);
    yg[base + (size_t)t * 768] = __float2bfloat16(out);
  }
}

// ---------------------------------------------------------------------------
// Launch
// ---------------------------------------------------------------------------
extern "C" void kernel_launch(void* const* d_in, const int* in_sizes, int n_in,
                              void* d_out, int out_size, void* d_ws, size_t ws_size,
                              hipStream_t stream) {
  const float* x       = (const float*)d_in[0];
  const float* A_log   = (const float*)d_in[1];
  const float* D_param = (const float*)d_in[2];
  const float* B_proj  = (const float*)d_in[3];
  const float* C_proj  = (const float*)d_in[4];
  const float* delta_w = (const float*)d_in[5];
  const float* delta_b = (const float*)d_in[6];
  const float* in_w    = (const float*)d_in[7];
  const float* in_b    = (const float*)d_in[8];
  const float* out_w   = (const float*)d_in[9];
  const float* out_b   = (const float*)d_in[10];
  const float* conv_w  = (const float*)d_in[11];
  const float* conv_b  = (const float*)d_in[12];

  char* ws = (char*)d_ws;
  __hip_bfloat16* xb       = (__hip_bfloat16*)(ws + 0);          // reused as yg later
  __hip_bfloat16* w_in_b   = (__hip_bfloat16*)(ws + 25165824);
  __hip_bfloat16* w_dbc_b  = (__hip_bfloat16*)(ws + 27525120);   // 896 x 768
  __hip_bfloat16* w_out_b  = (__hip_bfloat16*)(ws + 28901376);
  float*          A2       = (float*)(ws + 30081024);
  __hip_bfloat16* xin_b    = (__hip_bfloat16*)(ws + 30130176);
  __hip_bfloat16* z_b      = (__hip_bfloat16*)(ws + 55296000);
  __hip_bfloat16* xconv_b  = (__hip_bfloat16*)(ws + 80461824);
  __hip_bfloat16* delta_bf = (__hip_bfloat16*)(ws + 105627648);
  float*          Bsel     = (float*)(ws + 130793472);
  float*          Csel     = (float*)(ws + 131842048);
  float*          sumdt    = (float*)(ws + 132890624);
  float*          Sbuf     = (float*)(ws + 133677056);
  float*          Hin      = (float*)(ws + 146259968);
  __hip_bfloat16* yg       = xb;  // x (bf16) dead after in_proj GEMM

  const int BLD = BATCH * SEQL * D_MODEL;  // 12,582,912

  // 1. prep: x->bf16, weights->bf16, A2
  prep_all<<<21936, 256, 0, stream>>>(x, in_w, delta_w, B_proj, C_proj, out_w, A_log,
                                      xb, w_in_b, w_dbc_b, w_out_b, A2);
  // 2. in_proj GEMM [16384,1536] : 128 x 12 tiles = 1536 blocks (2 rounds)
  gemm128tb<0><<<1536, 256, 0, stream>>>(xb, w_in_b, in_b, xin_b, z_b, nullptr, 12);
  // 3. depthwise conv + silu (short8)
  conv_silu8<<<BLD / 8 / 256, 256, 0, stream>>>(xin_b, conv_w, conv_b, xconv_b);
  // 4. delta/B/C GEMM [16384,896] : 128 x 7 tiles = 896 blocks
  gemm128tb<1><<<896, 256, 0, stream>>>(xconv_b, w_dbc_b, delta_b, delta_bf, Bsel, Csel, 7);
  // 5-7. chunked scan
  scan_pass1<<<dim3(3, BATCH, NCHUNK), 256, 0, stream>>>(delta_bf, xconv_b, Bsel, A2, sumdt, Sbuf);
  scan_carry<<<384, 256, 0, stream>>>(sumdt, Sbuf, A2, Hin);
  scan_pass3<<<dim3(3, BATCH, NCHUNK), 256, 0, stream>>>(delta_bf, xconv_b, z_b, Bsel, Csel, A2,
                                                         Hin, D_param, yg);
  // 8. out_proj GEMM [16384,768] : 128 x 6 tiles = 768 blocks
  gemm128tb<2><<<768, 256, 0, stream>>>(yg, w_out_b, out_b, (float*)d_out, nullptr, nullptr, 6);
}